// Round 1
// baseline (582.437 us; speedup 1.0000x reference)
//
#include <hip/hip_runtime.h>

#define B_ 16
#define C_ 128
#define N_ 16384
#define LOG2E 1.4426950408889634f

typedef short bf16x8 __attribute__((ext_vector_type(8)));
typedef float f32x4 __attribute__((ext_vector_type(4)));

__device__ __forceinline__ ushort f2bf(float f) {
    union { float f; unsigned u; } v; v.f = f;
    unsigned r = (v.u + 0x7FFFu + ((v.u >> 16) & 1u)) >> 16;
    return (ushort)r;
}
__device__ __forceinline__ float bf2f(ushort h) {
    union { unsigned u; float f; } v; v.u = ((unsigned)h) << 16;
    return v.f;
}

// ---------------- K0: pack qkv_w fp32 -> bf16 ----------------
__global__ void k_pack(const float* __restrict__ w, ushort* __restrict__ wbf, int n) {
    int i = blockIdx.x * 256 + threadIdx.x;
    if (i < n) wbf[i] = f2bf(w[i]);
}

// ---------------- K1: GroupNorm stats (per b,g over 4ch x 16384) ----------------
__global__ void k_stats(const float* __restrict__ x, float* __restrict__ mu,
                        float* __restrict__ rstd) {
    int bg = blockIdx.x;  // b*32+g ; group data is contiguous: 4*N_ floats
    const float4* p = (const float4*)(x + (size_t)bg * (4 * N_));
    float s = 0.f, s2 = 0.f;
    for (int i = threadIdx.x; i < N_; i += 256) {  // 4*N_/4 float4s
        float4 v = p[i];
        s  += v.x + v.y + v.z + v.w;
        s2 += v.x * v.x + v.y * v.y + v.z * v.z + v.w * v.w;
    }
    #pragma unroll
    for (int d = 32; d > 0; d >>= 1) { s += __shfl_xor(s, d); s2 += __shfl_xor(s2, d); }
    __shared__ float ls[4], ls2[4];
    int wid = threadIdx.x >> 6, lane = threadIdx.x & 63;
    if (lane == 0) { ls[wid] = s; ls2[wid] = s2; }
    __syncthreads();
    if (threadIdx.x == 0) {
        float S = ls[0] + ls[1] + ls[2] + ls[3];
        float S2 = ls2[0] + ls2[1] + ls2[2] + ls2[3];
        float m = S / 65536.f;
        float var = S2 / 65536.f - m * m;
        mu[bg] = m;
        rstd[bg] = rsqrtf(var + 1e-5f);
    }
}

// ---------------- K1.5: xnT[b][n][c] bf16 (normalized, transposed) ----------------
__global__ void k_xnt(const float* __restrict__ x, const float* __restrict__ gnw,
                      const float* __restrict__ gnb, const float* __restrict__ mu,
                      const float* __restrict__ rstd, ushort* __restrict__ xnT) {
    int blk = blockIdx.x;
    int b = blk >> 7, n0 = (blk & 127) << 7;  // 128 n per block
    int tid = threadIdx.x;
    int np = tid & 63, cq = tid >> 6;  // thread: 2 n rows, 32 channels
    int n = n0 + np * 2;
    const float* xb = x + (size_t)b * C_ * N_;
    unsigned w0[16], w1[16];
    #pragma unroll
    for (int i = 0; i < 32; ++i) {
        int c = cq * 32 + i;
        float sc = rstd[b * 32 + (c >> 2)] * gnw[c];
        float bi = gnb[c] - mu[b * 32 + (c >> 2)] * sc;
        float2 v = *(const float2*)(xb + (size_t)c * N_ + n);
        ushort a0 = f2bf(v.x * sc + bi);
        ushort a1 = f2bf(v.y * sc + bi);
        if (i & 1) { w0[i >> 1] |= ((unsigned)a0) << 16; w1[i >> 1] |= ((unsigned)a1) << 16; }
        else       { w0[i >> 1] = a0;                     w1[i >> 1] = a1; }
    }
    ushort* r0 = xnT + ((size_t)(b * N_ + n)) * C_ + cq * 32;
    ushort* r1 = r0 + C_;
    #pragma unroll
    for (int q = 0; q < 4; ++q) {
        uint4 t0; t0.x = w0[q*4]; t0.y = w0[q*4+1]; t0.z = w0[q*4+2]; t0.w = w0[q*4+3];
        uint4 t1; t1.x = w1[q*4]; t1.y = w1[q*4+1]; t1.z = w1[q*4+2]; t1.w = w1[q*4+3];
        ((uint4*)r0)[q] = t0;
        ((uint4*)r1)[q] = t1;
    }
}

// ---------------- K2: qkv MFMA + exp(q) store + qsum/ctx partials ----------------
__global__ __launch_bounds__(256) void k_main(
    const ushort* __restrict__ xnT, const ushort* __restrict__ wbf,
    ushort* __restrict__ eqT, float* __restrict__ qsumP, float* __restrict__ ctxP) {
    int blk = blockIdx.x;
    int b = blk >> 6, nb = blk & 63;  // 64 blocks per batch, 256 n each
    int tid = threadIdx.x;
    int wid = tid >> 6, lane = tid & 63;
    int l15 = lane & 15, lg = lane >> 4;

    __shared__ ushort ksm[4][32][66];
    __shared__ ushort vls[4][32][66];
    __shared__ float qs[4][128];

    for (int i = tid; i < 512; i += 256) ((float*)qs)[i] = 0.f;

    float cacc[4][4] = {};
    int d0 = ((tid >> 3) & 7) * 4, e0 = (tid & 7) * 4;  // ctx ownership: head=wid
    __syncthreads();

    for (int it = 0; it < 4; ++it) {
        int n_lane = nb * 256 + it * 64 + wid * 16 + l15;
        int nl = wid * 16 + l15;  // LDS n column
        const ushort* xr = xnT + (size_t)(b * N_ + n_lane) * C_;
        bf16x8 xb[4];
        #pragma unroll
        for (int kc = 0; kc < 4; ++kc) xb[kc] = *(const bf16x8*)(xr + kc * 32 + lg * 8);

        // ---- q o-tiles 0..7 (o = 0..127): exp, store, qsum partial
        #pragma unroll
        for (int ot = 0; ot < 8; ++ot) {
            f32x4 acc = {0.f, 0.f, 0.f, 0.f};
            const ushort* wr = wbf + (size_t)(ot * 16 + l15) * C_;
            #pragma unroll
            for (int kc = 0; kc < 4; ++kc) {
                bf16x8 a = *(const bf16x8*)(wr + kc * 32 + lg * 8);
                acc = __builtin_amdgcn_mfma_f32_16x16x32_bf16(a, xb[kc], acc, 0, 0, 0);
            }
            float e[4];
            #pragma unroll
            for (int r = 0; r < 4; ++r) e[r] = __expf(acc[r]);
            unsigned p0 = (unsigned)f2bf(e[0]) | ((unsigned)f2bf(e[1]) << 16);
            unsigned p1 = (unsigned)f2bf(e[2]) | ((unsigned)f2bf(e[3]) << 16);
            ushort* ep = eqT + (size_t)(b * N_ + n_lane) * 128 + ot * 16 + lg * 4;
            uint2 pk; pk.x = p0; pk.y = p1;
            *(uint2*)ep = pk;
            #pragma unroll
            for (int r = 0; r < 4; ++r) {
                float s = e[r];
                s += __shfl_xor(s, 1); s += __shfl_xor(s, 2);
                s += __shfl_xor(s, 4); s += __shfl_xor(s, 8);
                if (l15 == 0) qs[wid][ot * 16 + lg * 4 + r] += s;
            }
        }

        // ---- k head-pairs (o = 128..255): softmax over d=32, -> LDS bf16
        #pragma unroll
        for (int hp = 0; hp < 4; ++hp) {
            f32x4 a0v = {0,0,0,0}, a1v = {0,0,0,0};
            const ushort* w0r = wbf + (size_t)((8 + 2 * hp) * 16 + l15) * C_;
            const ushort* w1r = wbf + (size_t)((9 + 2 * hp) * 16 + l15) * C_;
            #pragma unroll
            for (int kc = 0; kc < 4; ++kc) {
                bf16x8 a0f = *(const bf16x8*)(w0r + kc * 32 + lg * 8);
                bf16x8 a1f = *(const bf16x8*)(w1r + kc * 32 + lg * 8);
                a0v = __builtin_amdgcn_mfma_f32_16x16x32_bf16(a0f, xb[kc], a0v, 0, 0, 0);
                a1v = __builtin_amdgcn_mfma_f32_16x16x32_bf16(a1f, xb[kc], a1v, 0, 0, 0);
            }
            float ek[8]; float s = 0.f;
            #pragma unroll
            for (int r = 0; r < 4; ++r) { ek[r] = __expf(a0v[r]); s += ek[r]; }
            #pragma unroll
            for (int r = 0; r < 4; ++r) { ek[4 + r] = __expf(a1v[r]); s += ek[4 + r]; }
            s += __shfl_xor(s, 16);
            s += __shfl_xor(s, 32);
            float rinv = 1.f / s;
            #pragma unroll
            for (int r = 0; r < 4; ++r) {
                ksm[hp][lg * 4 + r][nl]      = f2bf(ek[r] * rinv);
                ksm[hp][16 + lg * 4 + r][nl] = f2bf(ek[4 + r] * rinv);
            }
        }

        // ---- v o-tiles 16..23 (o = 256..383) -> LDS bf16
        #pragma unroll
        for (int ot = 16; ot < 24; ++ot) {
            f32x4 acc = {0,0,0,0};
            const ushort* wr = wbf + (size_t)(ot * 16 + l15) * C_;
            #pragma unroll
            for (int kc = 0; kc < 4; ++kc) {
                bf16x8 a = *(const bf16x8*)(wr + kc * 32 + lg * 8);
                acc = __builtin_amdgcn_mfma_f32_16x16x32_bf16(a, xb[kc], acc, 0, 0, 0);
            }
            int hv = (ot - 16) >> 1, eb = ((ot - 16) & 1) * 16 + lg * 4;
            #pragma unroll
            for (int r = 0; r < 4; ++r) vls[hv][eb + r][nl] = f2bf(acc[r]);
        }
        __syncthreads();

        // ---- ctx partial accumulate over this iteration's 64 n
        int h_t = wid;
        for (int nn = 0; nn < 64; nn += 2) {
            float kvv[4][2], vvv[4][2];
            #pragma unroll
            for (int i = 0; i < 4; ++i) {
                unsigned wk = *(const unsigned*)&ksm[h_t][d0 + i][nn];
                kvv[i][0] = bf2f((ushort)(wk & 0xffffu)); kvv[i][1] = bf2f((ushort)(wk >> 16));
                unsigned wv = *(const unsigned*)&vls[h_t][e0 + i][nn];
                vvv[i][0] = bf2f((ushort)(wv & 0xffffu)); vvv[i][1] = bf2f((ushort)(wv >> 16));
            }
            #pragma unroll
            for (int i = 0; i < 4; ++i)
                #pragma unroll
                for (int j = 0; j < 4; ++j)
                    cacc[i][j] += kvv[i][0] * vvv[j][0] + kvv[i][1] * vvv[j][1];
        }
        __syncthreads();
    }

    if (tid < 128)
        qsumP[(size_t)blk * 128 + tid] = qs[0][tid] + qs[1][tid] + qs[2][tid] + qs[3][tid];
    float* cp = ctxP + (size_t)blk * 4096 + wid * 1024;
    #pragma unroll
    for (int i = 0; i < 4; ++i)
        #pragma unroll
        for (int j = 0; j < 4; ++j)
            cp[(d0 + i) * 32 + (e0 + j)] = cacc[i][j];
}

// ---------------- K3: combine partials, build M''[b][c][hd] bf16 ----------------
__global__ void k_comb(const float* __restrict__ ctxP, const float* __restrict__ qsumP,
                       const float* __restrict__ projw, ushort* __restrict__ mpp) {
    int b = blockIdx.x, tid = threadIdx.x;
    __shared__ float ctx[4096];
    __shared__ float qinv[128];
    for (int i = tid; i < 4096; i += 256) {
        float s = 0.f;
        const float* p = ctxP + (size_t)b * 64 * 4096 + i;
        for (int q = 0; q < 64; ++q) s += p[(size_t)q * 4096];
        ctx[i] = s;
    }
    if (tid < 128) {
        float s = 0.f;
        const float* p = qsumP + (size_t)b * 64 * 128 + tid;
        for (int q = 0; q < 64; ++q) s += p[q * 128];
        qinv[tid] = 1.f / s;
    }
    __syncthreads();
    int c = tid >> 1, hd0 = (tid & 1) * 64;
    unsigned ow[32];
    for (int k = 0; k < 64; ++k) {
        int hd = hd0 + k, h = hd >> 5, d = hd & 31;
        const float* pw = projw + c * 128 + h * 32;
        const float* cx = ctx + h * 1024 + d * 32;
        float s = 0.f;
        #pragma unroll 8
        for (int e = 0; e < 32; ++e) s += pw[e] * cx[e];
        s *= qinv[hd];
        ushort bv = f2bf(s);
        if (k & 1) ow[k >> 1] |= ((unsigned)bv) << 16; else ow[k >> 1] = bv;
    }
    ushort* dst = mpp + ((size_t)(b * 128 + c)) * 128 + hd0;
    #pragma unroll
    for (int q = 0; q < 8; ++q) {
        uint4 t; t.x = ow[q*4]; t.y = ow[q*4+1]; t.z = ow[q*4+2]; t.w = ow[q*4+3];
        ((uint4*)dst)[q] = t;
    }
}

// ---------------- K4: out = expq . M''^T + proj_b + x ----------------
__global__ __launch_bounds__(256) void k_final(
    const ushort* __restrict__ eqT, const ushort* __restrict__ mpp,
    const float* __restrict__ projb, const float* __restrict__ x,
    float* __restrict__ out) {
    int blk = blockIdx.x;
    int b = blk >> 6, nb = blk & 63;
    int tid = threadIdx.x, wid = tid >> 6, lane = tid & 63;
    int l15 = lane & 15, lg = lane >> 4;
    #pragma unroll
    for (int j = 0; j < 4; ++j) {
        int ntb = nb * 256 + wid * 64 + j * 16;
        const ushort* ar = eqT + (size_t)(b * N_ + ntb + l15) * 128;
        bf16x8 af[4];
        #pragma unroll
        for (int kc = 0; kc < 4; ++kc) af[kc] = *(const bf16x8*)(ar + kc * 32 + lg * 8);
        #pragma unroll
        for (int ct = 0; ct < 8; ++ct) {
            f32x4 acc = {0,0,0,0};
            const ushort* br = mpp + (size_t)(b * 128 + ct * 16 + l15) * 128;
            #pragma unroll
            for (int kc = 0; kc < 4; ++kc) {
                bf16x8 bfg = *(const bf16x8*)(br + kc * 32 + lg * 8);
                acc = __builtin_amdgcn_mfma_f32_16x16x32_bf16(af[kc], bfg, acc, 0, 0, 0);
            }
            int c = ct * 16 + l15;
            int nr = ntb + lg * 4;
            size_t off = (size_t)(b * C_ + c) * N_ + nr;
            float4 xv = *(const float4*)(x + off);
            float pb = projb[c];
            float4 o4;
            o4.x = acc[0] + pb + xv.x;
            o4.y = acc[1] + pb + xv.y;
            o4.z = acc[2] + pb + xv.z;
            o4.w = acc[3] + pb + xv.w;
            *(float4*)(out + off) = o4;
        }
    }
}

extern "C" void kernel_launch(void* const* d_in, const int* in_sizes, int n_in,
                              void* d_out, int out_size, void* d_ws, size_t ws_size,
                              hipStream_t stream) {
    const float* x     = (const float*)d_in[0];
    const float* gnw   = (const float*)d_in[1];
    const float* gnb   = (const float*)d_in[2];
    const float* qkvw  = (const float*)d_in[3];
    const float* projw = (const float*)d_in[4];
    const float* projb = (const float*)d_in[5];
    float* out = (float*)d_out;

    char* ws = (char*)d_ws;
    ushort* wbf   = (ushort*)(ws);                // 98,304 B
    float*  mu    = (float*)(ws + 98304);         // 2,048 B
    float*  rstd  = (float*)(ws + 100352);        // 2,048 B
    float*  qsumP = (float*)(ws + 102400);        // 524,288 B
    ushort* mpp   = (ushort*)(ws + 626688);       // 524,288 B
    float*  ctxP  = (float*)(ws + 1150976);       // 16,777,216 B
    ushort* eqT   = (ushort*)(ws + 17928192);     // 67,108,864 B  (end: 85,037,056)
    // xnT (67 MB) parked in d_out scratch; fully rewritten by k_final afterwards.
    ushort* xnT   = (ushort*)d_out;

    k_pack <<<192,  256, 0, stream>>>(qkvw, wbf, 384 * 128);
    k_stats<<<512,  256, 0, stream>>>(x, mu, rstd);
    k_xnt  <<<2048, 256, 0, stream>>>(x, gnw, gnb, mu, rstd, xnT);
    k_main <<<1024, 256, 0, stream>>>(xnT, wbf, eqT, qsumP, ctxP);
    k_comb <<<16,   256, 0, stream>>>(ctxP, qsumP, projw, mpp);
    k_final<<<1024, 256, 0, stream>>>(eqT, mpp, projb, x, out);
}

// Round 3
// 396.814 us; speedup vs baseline: 1.4678x; 1.4678x over previous
//
#include <hip/hip_runtime.h>

// R3: bisect of R2's failure. The R1-verified k_xnt (separate normalize+transpose
// kernel, xnT in d_out scratch) is restored verbatim; k_main keeps R2's new
// structure: o-tiles split across waves (weights register-resident), ctx via
// MFMA from ksm/vls LDS, register qsum accumulators.

#define B_ 16
#define C_ 128
#define N_ 16384

typedef short bf16x8 __attribute__((ext_vector_type(8)));
typedef float f32x4 __attribute__((ext_vector_type(4)));
typedef unsigned u32x2 __attribute__((ext_vector_type(2)));

__device__ __forceinline__ ushort f2bf(float f) {
    union { float f; unsigned u; } v; v.f = f;
    unsigned r = (v.u + 0x7FFFu + ((v.u >> 16) & 1u)) >> 16;
    return (ushort)r;
}

// ---------------- K0: pack qkv_w fp32 -> bf16 ----------------
__global__ void k_pack(const float* __restrict__ w, ushort* __restrict__ wbf, int n) {
    int i = blockIdx.x * 256 + threadIdx.x;
    if (i < n) wbf[i] = f2bf(w[i]);
}

// ---------------- K1: GroupNorm stats (R1 verbatim) ----------------
__global__ void k_stats(const float* __restrict__ x, float* __restrict__ mu,
                        float* __restrict__ rstd) {
    int bg = blockIdx.x;  // b*32+g ; group data contiguous: 4*N_ floats
    const float4* p = (const float4*)(x + (size_t)bg * (4 * N_));
    float s = 0.f, s2 = 0.f;
    for (int i = threadIdx.x; i < N_; i += 256) {
        float4 v = p[i];
        s  += v.x + v.y + v.z + v.w;
        s2 += v.x * v.x + v.y * v.y + v.z * v.z + v.w * v.w;
    }
    #pragma unroll
    for (int d = 32; d > 0; d >>= 1) { s += __shfl_xor(s, d); s2 += __shfl_xor(s2, d); }
    __shared__ float ls[4], ls2[4];
    int wid = threadIdx.x >> 6, lane = threadIdx.x & 63;
    if (lane == 0) { ls[wid] = s; ls2[wid] = s2; }
    __syncthreads();
    if (threadIdx.x == 0) {
        float S = ls[0] + ls[1] + ls[2] + ls[3];
        float S2 = ls2[0] + ls2[1] + ls2[2] + ls2[3];
        float m = S / 65536.f;
        float var = S2 / 65536.f - m * m;
        mu[bg] = m;
        rstd[bg] = rsqrtf(var + 1e-5f);
    }
}

// ---------------- K1.5: xnT[b][n][c] bf16 (R1 verbatim) ----------------
__global__ void k_xnt(const float* __restrict__ x, const float* __restrict__ gnw,
                      const float* __restrict__ gnb, const float* __restrict__ mu,
                      const float* __restrict__ rstd, ushort* __restrict__ xnT) {
    int blk = blockIdx.x;
    int b = blk >> 7, n0 = (blk & 127) << 7;  // 128 n per block
    int tid = threadIdx.x;
    int np = tid & 63, cq = tid >> 6;  // thread: 2 n rows, 32 channels
    int n = n0 + np * 2;
    const float* xb = x + (size_t)b * C_ * N_;
    unsigned w0[16], w1[16];
    #pragma unroll
    for (int i = 0; i < 32; ++i) {
        int c = cq * 32 + i;
        float sc = rstd[b * 32 + (c >> 2)] * gnw[c];
        float bi = gnb[c] - mu[b * 32 + (c >> 2)] * sc;
        float2 v = *(const float2*)(xb + (size_t)c * N_ + n);
        ushort a0 = f2bf(v.x * sc + bi);
        ushort a1 = f2bf(v.y * sc + bi);
        if (i & 1) { w0[i >> 1] |= ((unsigned)a0) << 16; w1[i >> 1] |= ((unsigned)a1) << 16; }
        else       { w0[i >> 1] = a0;                     w1[i >> 1] = a1; }
    }
    ushort* r0 = xnT + ((size_t)(b * N_ + n)) * C_ + cq * 32;
    ushort* r1 = r0 + C_;
    #pragma unroll
    for (int q = 0; q < 4; ++q) {
        uint4 t0; t0.x = w0[q*4]; t0.y = w0[q*4+1]; t0.z = w0[q*4+2]; t0.w = w0[q*4+3];
        uint4 t1; t1.x = w1[q*4]; t1.y = w1[q*4+1]; t1.z = w1[q*4+2]; t1.w = w1[q*4+3];
        ((uint4*)r0)[q] = t0;
        ((uint4*)r1)[q] = t1;
    }
}

// ---------------- K2: qkv + exp(q) + ksm + v + MFMA-ctx, o-split across waves --------
// wave0: q0..q5 | wave1: q6,q7,k(h0),k(h1) | wave2: k(h2),k(h3),v16,v17 | wave3: v18..23

#define MFMA16(A, Bv, Cc) __builtin_amdgcn_mfma_f32_16x16x32_bf16(A, Bv, Cc, 0, 0, 0)

#define DO_Q(J, OT) do { \
    f32x4 acc = {0.f, 0.f, 0.f, 0.f}; \
    acc = MFMA16(wf[J][0], xb[0], acc); acc = MFMA16(wf[J][1], xb[1], acc); \
    acc = MFMA16(wf[J][2], xb[2], acc); acc = MFMA16(wf[J][3], xb[3], acc); \
    float e0 = __expf(acc[0]), e1 = __expf(acc[1]); \
    float e2 = __expf(acc[2]), e3 = __expf(acc[3]); \
    qacc[J][0] += e0; qacc[J][1] += e1; qacc[J][2] += e2; qacc[J][3] += e3; \
    u32x2 pkq; \
    pkq.x = (unsigned)f2bf(e0) | ((unsigned)f2bf(e1) << 16); \
    pkq.y = (unsigned)f2bf(e2) | ((unsigned)f2bf(e3) << 16); \
    *(u32x2*)(eqp + (OT) * 16) = pkq; \
} while (0)

#define DO_K(JLO, H) do { \
    f32x4 aL = {0.f, 0.f, 0.f, 0.f}, aH = {0.f, 0.f, 0.f, 0.f}; \
    aL = MFMA16(wf[JLO][0], xb[0], aL);     aH = MFMA16(wf[(JLO)+1][0], xb[0], aH); \
    aL = MFMA16(wf[JLO][1], xb[1], aL);     aH = MFMA16(wf[(JLO)+1][1], xb[1], aH); \
    aL = MFMA16(wf[JLO][2], xb[2], aL);     aH = MFMA16(wf[(JLO)+1][2], xb[2], aH); \
    aL = MFMA16(wf[JLO][3], xb[3], aL);     aH = MFMA16(wf[(JLO)+1][3], xb[3], aH); \
    float eL0 = __expf(aL[0]), eL1 = __expf(aL[1]), eL2 = __expf(aL[2]), eL3 = __expf(aL[3]); \
    float eH0 = __expf(aH[0]), eH1 = __expf(aH[1]), eH2 = __expf(aH[2]), eH3 = __expf(aH[3]); \
    float s = eL0 + eL1 + eL2 + eL3 + eH0 + eH1 + eH2 + eH3; \
    s += __shfl_xor(s, 16); s += __shfl_xor(s, 32); \
    float rinv = 1.f / s; \
    ksm[H][lg * 4 + 0][nloc] = f2bf(eL0 * rinv); \
    ksm[H][lg * 4 + 1][nloc] = f2bf(eL1 * rinv); \
    ksm[H][lg * 4 + 2][nloc] = f2bf(eL2 * rinv); \
    ksm[H][lg * 4 + 3][nloc] = f2bf(eL3 * rinv); \
    ksm[H][16 + lg * 4 + 0][nloc] = f2bf(eH0 * rinv); \
    ksm[H][16 + lg * 4 + 1][nloc] = f2bf(eH1 * rinv); \
    ksm[H][16 + lg * 4 + 2][nloc] = f2bf(eH2 * rinv); \
    ksm[H][16 + lg * 4 + 3][nloc] = f2bf(eH3 * rinv); \
} while (0)

#define DO_V(J, HV, EB) do { \
    f32x4 acc = {0.f, 0.f, 0.f, 0.f}; \
    acc = MFMA16(wf[J][0], xb[0], acc); acc = MFMA16(wf[J][1], xb[1], acc); \
    acc = MFMA16(wf[J][2], xb[2], acc); acc = MFMA16(wf[J][3], xb[3], acc); \
    vls[HV][(EB) + lg * 4 + 0][nloc] = f2bf(acc[0]); \
    vls[HV][(EB) + lg * 4 + 1][nloc] = f2bf(acc[1]); \
    vls[HV][(EB) + lg * 4 + 2][nloc] = f2bf(acc[2]); \
    vls[HV][(EB) + lg * 4 + 3][nloc] = f2bf(acc[3]); \
} while (0)

__global__ __launch_bounds__(256, 2) void k_main(
    const ushort* __restrict__ xnT, const ushort* __restrict__ wbf,
    ushort* __restrict__ eqT, float* __restrict__ qsumP, float* __restrict__ ctxP) {
    int blk = blockIdx.x;
    int b = blk >> 6, nb = blk & 63;
    int tid = threadIdx.x, wid = tid >> 6, lane = tid & 63;
    int l15 = lane & 15, lg = lane >> 4;

    __shared__ __align__(16) ushort ksm[4][32][72];  // [head][d][n(64)+pad]
    __shared__ __align__(16) ushort vls[4][32][72];  // [head][e][n(64)+pad]

    // weight fragments, register-resident for the whole kernel
    bf16x8 wf[6][4];
    {
        const ushort* wr = wbf + (size_t)(wid * 96 + l15) * 128 + lg * 8;
        #pragma unroll
        for (int j = 0; j < 6; ++j)
            #pragma unroll
            for (int kc = 0; kc < 4; ++kc)
                wf[j][kc] = *(const bf16x8*)(wr + j * 2048 + kc * 32);
    }

    float qacc[6][4];
    #pragma unroll
    for (int j = 0; j < 6; ++j)
        #pragma unroll
        for (int r = 0; r < 4; ++r) qacc[j][r] = 0.f;
    f32x4 cacc[2][2];
    #pragma unroll
    for (int di = 0; di < 2; ++di)
        #pragma unroll
        for (int ei = 0; ei < 2; ++ei) cacc[di][ei] = (f32x4){0.f, 0.f, 0.f, 0.f};

    for (int ch = 0; ch < 4; ++ch) {
        // ---- Phase B: per 16-n tile, xb from global xnT (R1-verified pattern)
        for (int nt = 0; nt < 4; ++nt) {
            int nloc = nt * 16 + l15;
            int ng = nb * 256 + ch * 64 + nloc;
            const ushort* xr = xnT + (size_t)(b * N_ + ng) * C_;
            bf16x8 xb[4];
            #pragma unroll
            for (int kc = 0; kc < 4; ++kc)
                xb[kc] = *(const bf16x8*)(xr + kc * 32 + lg * 8);
            ushort* eqp = eqT + ((size_t)b * N_ + ng) * 128 + lg * 4;

            if (wid == 0) {
                DO_Q(0, 0); DO_Q(1, 1); DO_Q(2, 2); DO_Q(3, 3); DO_Q(4, 4); DO_Q(5, 5);
            } else if (wid == 1) {
                DO_Q(0, 6); DO_Q(1, 7); DO_K(2, 0); DO_K(4, 1);
            } else if (wid == 2) {
                DO_K(0, 2); DO_K(2, 3); DO_V(4, 0, 0); DO_V(5, 0, 16);
            } else {
                DO_V(0, 1, 0); DO_V(1, 1, 16); DO_V(2, 2, 0);
                DO_V(3, 2, 16); DO_V(4, 3, 0); DO_V(5, 3, 16);
            }
        }
        __syncthreads();

        // ---- Phase C: ctx[d][e] += ksm . vls^T over this chunk's 64 n (MFMA)
        #pragma unroll
        for (int ks = 0; ks < 2; ++ks) {
            bf16x8 A0 = *(const bf16x8*)&ksm[wid][l15][ks * 32 + lg * 8];
            bf16x8 A1 = *(const bf16x8*)&ksm[wid][16 + l15][ks * 32 + lg * 8];
            bf16x8 B0 = *(const bf16x8*)&vls[wid][l15][ks * 32 + lg * 8];
            bf16x8 B1 = *(const bf16x8*)&vls[wid][16 + l15][ks * 32 + lg * 8];
            cacc[0][0] = MFMA16(A0, B0, cacc[0][0]);
            cacc[0][1] = MFMA16(A0, B1, cacc[0][1]);
            cacc[1][0] = MFMA16(A1, B0, cacc[1][0]);
            cacc[1][1] = MFMA16(A1, B1, cacc[1][1]);
        }
        __syncthreads();
    }

    // ---- qsum: reduce register accumulators over the 16 n-columns (l15 lanes)
    int nq = (wid == 0) ? 6 : (wid == 1 ? 2 : 0);
    #pragma unroll
    for (int j = 0; j < 6; ++j) {
        if (j < nq) {
            #pragma unroll
            for (int r = 0; r < 4; ++r) {
                float s = qacc[j][r];
                s += __shfl_xor(s, 1); s += __shfl_xor(s, 2);
                s += __shfl_xor(s, 4); s += __shfl_xor(s, 8);
                if (l15 == 0)
                    qsumP[(size_t)blk * 128 + (wid * 6 + j) * 16 + lg * 4 + r] = s;
            }
        }
    }
    // ---- ctx partials out (head = wid): D layout col=l15(e), row=lg*4+r(d)
    float* cp = ctxP + (size_t)blk * 4096 + wid * 1024;
    #pragma unroll
    for (int di = 0; di < 2; ++di)
        #pragma unroll
        for (int ei = 0; ei < 2; ++ei)
            #pragma unroll
            for (int r = 0; r < 4; ++r)
                cp[(di * 16 + lg * 4 + r) * 32 + ei * 16 + l15] = cacc[di][ei][r];
}

// ---------------- K3: combine partials, build M''[b][c][hd] bf16 ----------------
__global__ void k_comb(const float* __restrict__ ctxP, const float* __restrict__ qsumP,
                       const float* __restrict__ projw, ushort* __restrict__ mpp) {
    int b = blockIdx.x, tid = threadIdx.x;
    __shared__ float ctx[4096];
    __shared__ float qinv[128];
    for (int i = tid; i < 4096; i += 256) {
        float s = 0.f;
        const float* p = ctxP + (size_t)b * 64 * 4096 + i;
        for (int q = 0; q < 64; ++q) s += p[(size_t)q * 4096];
        ctx[i] = s;
    }
    if (tid < 128) {
        float s = 0.f;
        const float* p = qsumP + (size_t)b * 64 * 128 + tid;
        for (int q = 0; q < 64; ++q) s += p[q * 128];
        qinv[tid] = 1.f / s;
    }
    __syncthreads();
    int c = tid >> 1, hd0 = (tid & 1) * 64;
    unsigned ow[32];
    for (int k = 0; k < 64; ++k) {
        int hd = hd0 + k, h = hd >> 5, d = hd & 31;
        const float* pw = projw + c * 128 + h * 32;
        const float* cx = ctx + h * 1024 + d * 32;
        float s = 0.f;
        #pragma unroll 8
        for (int e = 0; e < 32; ++e) s += pw[e] * cx[e];
        s *= qinv[hd];
        ushort bv = f2bf(s);
        if (k & 1) ow[k >> 1] |= ((unsigned)bv) << 16; else ow[k >> 1] = bv;
    }
    ushort* dst = mpp + ((size_t)(b * 128 + c)) * 128 + hd0;
    #pragma unroll
    for (int q = 0; q < 8; ++q) {
        uint4 t; t.x = ow[q * 4]; t.y = ow[q * 4 + 1]; t.z = ow[q * 4 + 2]; t.w = ow[q * 4 + 3];
        ((uint4*)dst)[q] = t;
    }
}

// ---------------- K4: out = expq . M''^T + proj_b + x ----------------
__global__ __launch_bounds__(256) void k_final(
    const ushort* __restrict__ eqT, const ushort* __restrict__ mpp,
    const float* __restrict__ projb, const float* __restrict__ x,
    float* __restrict__ out) {
    int blk = blockIdx.x;
    int b = blk >> 6, nb = blk & 63;
    int tid = threadIdx.x, wid = tid >> 6, lane = tid & 63;
    int l15 = lane & 15, lg = lane >> 4;
    #pragma unroll
    for (int j = 0; j < 4; ++j) {
        int ntb = nb * 256 + wid * 64 + j * 16;
        const ushort* ar = eqT + (size_t)(b * N_ + ntb + l15) * 128;
        bf16x8 af[4];
        #pragma unroll
        for (int kc = 0; kc < 4; ++kc) af[kc] = *(const bf16x8*)(ar + kc * 32 + lg * 8);
        #pragma unroll
        for (int ct = 0; ct < 8; ++ct) {
            f32x4 acc = {0.f, 0.f, 0.f, 0.f};
            const ushort* br = mpp + (size_t)(b * 128 + ct * 16 + l15) * 128;
            #pragma unroll
            for (int kc = 0; kc < 4; ++kc) {
                bf16x8 bfg = *(const bf16x8*)(br + kc * 32 + lg * 8);
                acc = MFMA16(af[kc], bfg, acc);
            }
            int c = ct * 16 + l15;
            int nr = ntb + lg * 4;
            size_t off = (size_t)(b * C_ + c) * N_ + nr;
            float4 xv = *(const float4*)(x + off);
            float pb = projb[c];
            float4 o4;
            o4.x = acc[0] + pb + xv.x;
            o4.y = acc[1] + pb + xv.y;
            o4.z = acc[2] + pb + xv.z;
            o4.w = acc[3] + pb + xv.w;
            *(float4*)(out + off) = o4;
        }
    }
}

extern "C" void kernel_launch(void* const* d_in, const int* in_sizes, int n_in,
                              void* d_out, int out_size, void* d_ws, size_t ws_size,
                              hipStream_t stream) {
    const float* x     = (const float*)d_in[0];
    const float* gnw   = (const float*)d_in[1];
    const float* gnb   = (const float*)d_in[2];
    const float* qkvw  = (const float*)d_in[3];
    const float* projw = (const float*)d_in[4];
    const float* projb = (const float*)d_in[5];
    float* out = (float*)d_out;

    char* ws = (char*)d_ws;
    ushort* wbf   = (ushort*)(ws);                // 98,304 B
    float*  mu    = (float*)(ws + 98304);         // 2,048 B
    float*  rstd  = (float*)(ws + 100352);        // 2,048 B
    float*  qsumP = (float*)(ws + 102400);        // 524,288 B
    ushort* mpp   = (ushort*)(ws + 626688);       // 524,288 B
    float*  ctxP  = (float*)(ws + 1150976);       // 16,777,216 B
    ushort* eqT   = (ushort*)(ws + 17928192);     // 67,108,864 B (end: 85,037,056)
    // xnT (67 MB) parked in d_out scratch; fully rewritten by k_final afterwards.
    ushort* xnT   = (ushort*)d_out;

    k_pack <<<192,  256, 0, stream>>>(qkvw, wbf, 384 * 128);
    k_stats<<<512,  256, 0, stream>>>(x, mu, rstd);
    k_xnt  <<<2048, 256, 0, stream>>>(x, gnw, gnb, mu, rstd, xnT);
    k_main <<<1024, 256, 0, stream>>>(xnT, wbf, eqT, qsumP, ctxP);
    k_comb <<<16,   256, 0, stream>>>(ctxP, qsumP, projw, mpp);
    k_final<<<1024, 256, 0, stream>>>(eqT, mpp, projb, x, out);
}

// Round 5
// 284.088 us; speedup vs baseline: 2.0502x; 1.3968x over previous
//
#include <hip/hip_runtime.h>

// R5: R4 with the nontemporal builtin type fix (ext-vector f32x4 instead of
// HIP_vector_type float4 in k_final).
// R4 content: k_xnt fused into k_main via XOR-swizzled LDS transpose; k_final
// regridded 1024->4096 blocks; k_stats 1024 threads; k_red for ctxP reduction.

#define B_ 16
#define C_ 128
#define N_ 16384

typedef short bf16x8 __attribute__((ext_vector_type(8)));
typedef float f32x4 __attribute__((ext_vector_type(4)));
typedef unsigned u32x2 __attribute__((ext_vector_type(2)));

__device__ __forceinline__ ushort f2bf(float f) {
    union { float f; unsigned u; } v; v.f = f;
    unsigned r = (v.u + 0x7FFFu + ((v.u >> 16) & 1u)) >> 16;
    return (ushort)r;
}

// ---------------- K0: pack qkv_w fp32 -> bf16 ----------------
__global__ void k_pack(const float* __restrict__ w, ushort* __restrict__ wbf, int n) {
    int i = blockIdx.x * 256 + threadIdx.x;
    if (i < n) wbf[i] = f2bf(w[i]);
}

// ---------------- K1: GroupNorm stats -> folded per-(b,c) scale/bias ----------------
__global__ void k_stats(const float* __restrict__ x, const float* __restrict__ gnw,
                        const float* __restrict__ gnb, float* __restrict__ sc,
                        float* __restrict__ bi) {
    int bg = blockIdx.x;  // b*32+g ; group data contiguous: 4*N_ floats
    const float4* p = (const float4*)(x + (size_t)bg * (4 * N_));
    float s = 0.f, s2 = 0.f;
    for (int i = threadIdx.x; i < N_; i += 1024) {
        float4 v = p[i];
        s  += v.x + v.y + v.z + v.w;
        s2 += v.x * v.x + v.y * v.y + v.z * v.z + v.w * v.w;
    }
    #pragma unroll
    for (int d = 32; d > 0; d >>= 1) { s += __shfl_xor(s, d); s2 += __shfl_xor(s2, d); }
    __shared__ float ls[16], ls2[16];
    int wid = threadIdx.x >> 6, lane = threadIdx.x & 63;
    if (lane == 0) { ls[wid] = s; ls2[wid] = s2; }
    __syncthreads();
    if (threadIdx.x == 0) {
        float S = 0.f, S2 = 0.f;
        #pragma unroll
        for (int i = 0; i < 16; ++i) { S += ls[i]; S2 += ls2[i]; }
        float m = S / 65536.f;
        float var = S2 / 65536.f - m * m;
        float rs = rsqrtf(var + 1e-5f);
        int b = bg >> 5, g = bg & 31;
        #pragma unroll
        for (int i = 0; i < 4; ++i) {
            int c = g * 4 + i;
            float scv = rs * gnw[c];
            sc[b * 128 + c] = scv;
            bi[b * 128 + c] = gnb[c] - m * scv;
        }
    }
}

// ---------------- K2: fused normalize+transpose+qkv+exp(q)+ksm+v+MFMA-ctx ----------
// wave0: q0..q5 | wave1: q6,q7,k(h0),k(h1) | wave2: k(h2),k(h3),v16,v17 | wave3: v18..23

#define MFMA16(A, Bv, Cc) __builtin_amdgcn_mfma_f32_16x16x32_bf16(A, Bv, Cc, 0, 0, 0)

#define DO_Q(J, OT) do { \
    f32x4 acc = {0.f, 0.f, 0.f, 0.f}; \
    acc = MFMA16(wf[J][0], xb[0], acc); acc = MFMA16(wf[J][1], xb[1], acc); \
    acc = MFMA16(wf[J][2], xb[2], acc); acc = MFMA16(wf[J][3], xb[3], acc); \
    float e0 = __expf(acc[0]), e1 = __expf(acc[1]); \
    float e2 = __expf(acc[2]), e3 = __expf(acc[3]); \
    qacc[J][0] += e0; qacc[J][1] += e1; qacc[J][2] += e2; qacc[J][3] += e3; \
    u32x2 pkq; \
    pkq.x = (unsigned)f2bf(e0) | ((unsigned)f2bf(e1) << 16); \
    pkq.y = (unsigned)f2bf(e2) | ((unsigned)f2bf(e3) << 16); \
    *(u32x2*)(eqp + (OT) * 16) = pkq; \
} while (0)

#define DO_K(JLO, H) do { \
    f32x4 aL = {0.f, 0.f, 0.f, 0.f}, aH = {0.f, 0.f, 0.f, 0.f}; \
    aL = MFMA16(wf[JLO][0], xb[0], aL);     aH = MFMA16(wf[(JLO)+1][0], xb[0], aH); \
    aL = MFMA16(wf[JLO][1], xb[1], aL);     aH = MFMA16(wf[(JLO)+1][1], xb[1], aH); \
    aL = MFMA16(wf[JLO][2], xb[2], aL);     aH = MFMA16(wf[(JLO)+1][2], xb[2], aH); \
    aL = MFMA16(wf[JLO][3], xb[3], aL);     aH = MFMA16(wf[(JLO)+1][3], xb[3], aH); \
    float eL0 = __expf(aL[0]), eL1 = __expf(aL[1]), eL2 = __expf(aL[2]), eL3 = __expf(aL[3]); \
    float eH0 = __expf(aH[0]), eH1 = __expf(aH[1]), eH2 = __expf(aH[2]), eH3 = __expf(aH[3]); \
    float s = eL0 + eL1 + eL2 + eL3 + eH0 + eH1 + eH2 + eH3; \
    s += __shfl_xor(s, 16); s += __shfl_xor(s, 32); \
    float rinv = 1.f / s; \
    ksm[H][lg * 4 + 0][nloc] = f2bf(eL0 * rinv); \
    ksm[H][lg * 4 + 1][nloc] = f2bf(eL1 * rinv); \
    ksm[H][lg * 4 + 2][nloc] = f2bf(eL2 * rinv); \
    ksm[H][lg * 4 + 3][nloc] = f2bf(eL3 * rinv); \
    ksm[H][16 + lg * 4 + 0][nloc] = f2bf(eH0 * rinv); \
    ksm[H][16 + lg * 4 + 1][nloc] = f2bf(eH1 * rinv); \
    ksm[H][16 + lg * 4 + 2][nloc] = f2bf(eH2 * rinv); \
    ksm[H][16 + lg * 4 + 3][nloc] = f2bf(eH3 * rinv); \
} while (0)

#define DO_V(J, HV, EB) do { \
    f32x4 acc = {0.f, 0.f, 0.f, 0.f}; \
    acc = MFMA16(wf[J][0], xb[0], acc); acc = MFMA16(wf[J][1], xb[1], acc); \
    acc = MFMA16(wf[J][2], xb[2], acc); acc = MFMA16(wf[J][3], xb[3], acc); \
    vls[HV][(EB) + lg * 4 + 0][nloc] = f2bf(acc[0]); \
    vls[HV][(EB) + lg * 4 + 1][nloc] = f2bf(acc[1]); \
    vls[HV][(EB) + lg * 4 + 2][nloc] = f2bf(acc[2]); \
    vls[HV][(EB) + lg * 4 + 3][nloc] = f2bf(acc[3]); \
} while (0)

__global__ __launch_bounds__(256, 2) void k_main(
    const float* __restrict__ x, const ushort* __restrict__ wbf,
    const float* __restrict__ scA, const float* __restrict__ biA,
    ushort* __restrict__ eqT, float* __restrict__ qsumP, float* __restrict__ ctxP) {
    int blk = blockIdx.x;
    int b = blk >> 6, nb = blk & 63;
    int tid = threadIdx.x, wid = tid >> 6, lane = tid & 63;
    int l15 = lane & 15, lg = lane >> 4;

    // xs: 64 n-rows x 128 c (bf16), row = 256 B, byte col XOR-swizzled by (n&7)<<4
    __shared__ __align__(16) ushort xs[8192];        // 16 KB
    __shared__ __align__(16) ushort ksm[4][32][72];  // [head][d][n(64)+pad]
    __shared__ __align__(16) ushort vls[4][32][72];  // [head][e][n(64)+pad]

    // weight fragments, register-resident for the whole kernel
    bf16x8 wf[6][4];
    {
        const ushort* wr = wbf + (size_t)(wid * 96 + l15) * 128 + lg * 8;
        #pragma unroll
        for (int j = 0; j < 6; ++j)
            #pragma unroll
            for (int kc = 0; kc < 4; ++kc)
                wf[j][kc] = *(const bf16x8*)(wr + j * 2048 + kc * 32);
    }

    float qacc[6][4];
    #pragma unroll
    for (int j = 0; j < 6; ++j)
        #pragma unroll
        for (int r = 0; r < 4; ++r) qacc[j][r] = 0.f;
    f32x4 cacc[2][2];
    #pragma unroll
    for (int di = 0; di < 2; ++di)
        #pragma unroll
        for (int ei = 0; ei < 2; ++ei) cacc[di][ei] = (f32x4){0.f, 0.f, 0.f, 0.f};

    // Phase-A constants: thread (pk_, pcb) loads float4 (n = pk_*4..+3) of
    // channels c = pcb*8..+7, normalizes, register-transposes, b128-writes xs.
    const int pk_ = tid & 15, pcb = tid >> 4;
    const float* xrow = x + (size_t)b * (C_ * N_) + nb * 256 + pk_ * 4;
    float scv[8], biv[8];
    #pragma unroll
    for (int i = 0; i < 8; ++i) {
        scv[i] = scA[b * 128 + pcb * 8 + i];
        biv[i] = biA[b * 128 + pcb * 8 + i];
    }
    unsigned boffj[4];
    #pragma unroll
    for (int j = 0; j < 4; ++j) {
        int n = pk_ * 4 + j;
        boffj[j] = (unsigned)(n * 256 + ((pcb * 16) ^ ((n & 7) << 4)));
    }

    for (int ch = 0; ch < 4; ++ch) {
        // ---- Phase A: x -> normalized bf16 -> xs (swizzled [n][c])
        union { uint4 v; unsigned w[4]; } wj0, wj1, wj2, wj3;
        #pragma unroll
        for (int i = 0; i < 8; ++i) {
            float4 v = *(const float4*)(xrow + (size_t)(pcb * 8 + i) * N_ + ch * 64);
            float s = scv[i], t = biv[i];
            unsigned e0 = f2bf(v.x * s + t), e1 = f2bf(v.y * s + t);
            unsigned e2 = f2bf(v.z * s + t), e3 = f2bf(v.w * s + t);
            int wI = i >> 1;
            if (i & 1) {
                wj0.w[wI] |= e0 << 16; wj1.w[wI] |= e1 << 16;
                wj2.w[wI] |= e2 << 16; wj3.w[wI] |= e3 << 16;
            } else {
                wj0.w[wI] = e0; wj1.w[wI] = e1; wj2.w[wI] = e2; wj3.w[wI] = e3;
            }
        }
        *(uint4*)((char*)xs + boffj[0]) = wj0.v;
        *(uint4*)((char*)xs + boffj[1]) = wj1.v;
        *(uint4*)((char*)xs + boffj[2]) = wj2.v;
        *(uint4*)((char*)xs + boffj[3]) = wj3.v;
        __syncthreads();

        // ---- Phase B: per 16-n tile, xb fragments via swizzled b128 reads
        for (int nt = 0; nt < 4; ++nt) {
            int row = nt * 16 + l15;
            bf16x8 xb[4];
            #pragma unroll
            for (int kc = 0; kc < 4; ++kc) {
                unsigned off = (unsigned)(row * 256 +
                    (((kc * 4 + lg) * 16) ^ ((row & 7) << 4)));
                xb[kc] = *(const bf16x8*)((const char*)xs + off);
            }
            int nloc = nt * 16 + l15;
            int ng = nb * 256 + ch * 64 + nloc;
            ushort* eqp = eqT + ((size_t)b * N_ + ng) * 128 + lg * 4;

            if (wid == 0) {
                DO_Q(0, 0); DO_Q(1, 1); DO_Q(2, 2); DO_Q(3, 3); DO_Q(4, 4); DO_Q(5, 5);
            } else if (wid == 1) {
                DO_Q(0, 6); DO_Q(1, 7); DO_K(2, 0); DO_K(4, 1);
            } else if (wid == 2) {
                DO_K(0, 2); DO_K(2, 3); DO_V(4, 0, 0); DO_V(5, 0, 16);
            } else {
                DO_V(0, 1, 0); DO_V(1, 1, 16); DO_V(2, 2, 0);
                DO_V(3, 2, 16); DO_V(4, 3, 0); DO_V(5, 3, 16);
            }
        }
        __syncthreads();

        // ---- Phase C: ctx[d][e] += ksm . vls^T over this chunk's 64 n (MFMA)
        #pragma unroll
        for (int ks = 0; ks < 2; ++ks) {
            bf16x8 A0 = *(const bf16x8*)&ksm[wid][l15][ks * 32 + lg * 8];
            bf16x8 A1 = *(const bf16x8*)&ksm[wid][16 + l15][ks * 32 + lg * 8];
            bf16x8 B0 = *(const bf16x8*)&vls[wid][l15][ks * 32 + lg * 8];
            bf16x8 B1 = *(const bf16x8*)&vls[wid][16 + l15][ks * 32 + lg * 8];
            cacc[0][0] = MFMA16(A0, B0, cacc[0][0]);
            cacc[0][1] = MFMA16(A0, B1, cacc[0][1]);
            cacc[1][0] = MFMA16(A1, B0, cacc[1][0]);
            cacc[1][1] = MFMA16(A1, B1, cacc[1][1]);
        }
        __syncthreads();
    }

    // ---- qsum: reduce register accumulators over the 16 n-columns (l15 lanes)
    int nq = (wid == 0) ? 6 : (wid == 1 ? 2 : 0);
    #pragma unroll
    for (int j = 0; j < 6; ++j) {
        if (j < nq) {
            #pragma unroll
            for (int r = 0; r < 4; ++r) {
                float s = qacc[j][r];
                s += __shfl_xor(s, 1); s += __shfl_xor(s, 2);
                s += __shfl_xor(s, 4); s += __shfl_xor(s, 8);
                if (l15 == 0)
                    qsumP[(size_t)blk * 128 + (wid * 6 + j) * 16 + lg * 4 + r] = s;
            }
        }
    }
    // ---- ctx partials out (head = wid): D layout col=l15(e), row=lg*4+r(d)
    float* cp = ctxP + (size_t)blk * 4096 + wid * 1024;
    #pragma unroll
    for (int di = 0; di < 2; ++di)
        #pragma unroll
        for (int ei = 0; ei < 2; ++ei)
            #pragma unroll
            for (int r = 0; r < 4; ++r)
                cp[(di * 16 + lg * 4 + r) * 32 + ei * 16 + l15] = cacc[di][ei][r];
}

// ---------------- K2.5: reduce ctxP over the 64 n-blocks (into q=0 slice) ----
__global__ void k_red(float* __restrict__ ctxP) {
    int blk = blockIdx.x;  // B*8
    int b = blk >> 3, sl = blk & 7;
    float* base = ctxP + (size_t)b * 64 * 4096;
    #pragma unroll
    for (int r = 0; r < 2; ++r) {
        int i = sl * 512 + r * 256 + threadIdx.x;
        float s = 0.f;
        for (int q = 0; q < 64; ++q) s += base[(size_t)q * 4096 + i];
        base[i] = s;
    }
}

// ---------------- K3: combine partials, build M''[b][c][hd] bf16 ----------------
__global__ void k_comb(const float* __restrict__ ctxP, const float* __restrict__ qsumP,
                       const float* __restrict__ projw, ushort* __restrict__ mpp) {
    int b = blockIdx.x, tid = threadIdx.x;
    __shared__ float ctx[4096];
    __shared__ float qinv[128];
    for (int i = tid; i < 4096; i += 256)
        ctx[i] = ctxP[(size_t)b * 64 * 4096 + i];
    if (tid < 128) {
        float s = 0.f;
        const float* p = qsumP + (size_t)b * 64 * 128 + tid;
        for (int q = 0; q < 64; ++q) s += p[q * 128];
        qinv[tid] = 1.f / s;
    }
    __syncthreads();
    int c = tid >> 1, hd0 = (tid & 1) * 64;
    unsigned ow[32];
    for (int k = 0; k < 64; ++k) {
        int hd = hd0 + k, h = hd >> 5, d = hd & 31;
        const float* pw = projw + c * 128 + h * 32;
        const float* cx = ctx + h * 1024 + d * 32;
        float s = 0.f;
        #pragma unroll 8
        for (int e = 0; e < 32; ++e) s += pw[e] * cx[e];
        s *= qinv[hd];
        ushort bv = f2bf(s);
        if (k & 1) ow[k >> 1] |= ((unsigned)bv) << 16; else ow[k >> 1] = bv;
    }
    ushort* dst = mpp + ((size_t)(b * 128 + c)) * 128 + hd0;
    #pragma unroll
    for (int q = 0; q < 8; ++q) {
        uint4 t; t.x = ow[q * 4]; t.y = ow[q * 4 + 1]; t.z = ow[q * 4 + 2]; t.w = ow[q * 4 + 3];
        ((uint4*)dst)[q] = t;
    }
}

// ---------------- K4: out = expq . M''^T + proj_b + x (64 n per block) ----------------
__global__ __launch_bounds__(256) void k_final(
    const ushort* __restrict__ eqT, const ushort* __restrict__ mpp,
    const float* __restrict__ projb, const float* __restrict__ x,
    float* __restrict__ out) {
    int blk = blockIdx.x;
    int b = blk >> 8, nb = blk & 255;
    int tid = threadIdx.x, wid = tid >> 6, lane = tid & 63;
    int l15 = lane & 15, lg = lane >> 4;
    int ntb = nb * 64 + wid * 16;
    const ushort* ar = eqT + (size_t)(b * N_ + ntb + l15) * 128;
    bf16x8 af[4];
    #pragma unroll
    for (int kc = 0; kc < 4; ++kc) af[kc] = *(const bf16x8*)(ar + kc * 32 + lg * 8);
    #pragma unroll
    for (int ct = 0; ct < 8; ++ct) {
        f32x4 acc = {0.f, 0.f, 0.f, 0.f};
        const ushort* br = mpp + (size_t)(b * 128 + ct * 16 + l15) * 128;
        #pragma unroll
        for (int kc = 0; kc < 4; ++kc) {
            bf16x8 bfg = *(const bf16x8*)(br + kc * 32 + lg * 8);
            acc = MFMA16(af[kc], bfg, acc);
        }
        int c = ct * 16 + l15;
        int nr = ntb + lg * 4;
        size_t off = (size_t)(b * C_ + c) * N_ + nr;
        f32x4 xv = __builtin_nontemporal_load((const f32x4*)(x + off));
        float pb = projb[c];
        f32x4 o4;
        o4[0] = acc[0] + pb + xv[0];
        o4[1] = acc[1] + pb + xv[1];
        o4[2] = acc[2] + pb + xv[2];
        o4[3] = acc[3] + pb + xv[3];
        __builtin_nontemporal_store(o4, (f32x4*)(out + off));
    }
}

extern "C" void kernel_launch(void* const* d_in, const int* in_sizes, int n_in,
                              void* d_out, int out_size, void* d_ws, size_t ws_size,
                              hipStream_t stream) {
    const float* x     = (const float*)d_in[0];
    const float* gnw   = (const float*)d_in[1];
    const float* gnb   = (const float*)d_in[2];
    const float* qkvw  = (const float*)d_in[3];
    const float* projw = (const float*)d_in[4];
    const float* projb = (const float*)d_in[5];
    float* out = (float*)d_out;

    char* ws = (char*)d_ws;
    ushort* wbf   = (ushort*)(ws);                // 98,304 B
    float*  qsumP = (float*)(ws + 102400);        // 524,288 B
    ushort* mpp   = (ushort*)(ws + 626688);       // 524,288 B
    // sc/bi overlap mpp (disjoint lifetimes: k_stats writes, k_main reads,
    // THEN k_comb writes mpp; re-established identically every replay)
    float*  sc    = (float*)(ws + 626688);        // 8,192 B
    float*  bi    = (float*)(ws + 634880);        // 8,192 B
    float*  ctxP  = (float*)(ws + 1150976);       // 16,777,216 B
    ushort* eqT   = (ushort*)(ws + 17928192);     // 67,108,864 B (end: 85,037,056)

    k_pack <<<192,  256,  0, stream>>>(qkvw, wbf, 384 * 128);
    k_stats<<<512,  1024, 0, stream>>>(x, gnw, gnb, sc, bi);
    k_main <<<1024, 256,  0, stream>>>(x, wbf, sc, bi, eqT, qsumP, ctxP);
    k_red  <<<128,  256,  0, stream>>>(ctxP);
    k_comb <<<16,   256,  0, stream>>>(ctxP, qsumP, projw, mpp);
    k_final<<<4096, 256,  0, stream>>>(eqT, mpp, projb, x, out);
}

// Round 6
// 281.208 us; speedup vs baseline: 2.0712x; 1.0102x over previous
//
#include <hip/hip_runtime.h>

// R6: k_final restructured for memory-level parallelism — phase-split
// (all MFMAs -> all x loads -> all stores), explicit acc[8]/xv[8] arrays to
// force ~100 VGPR and 8-deep load pipelining (R5 had VGPR=40, serialized
// loads, 2.4 TB/s). Nontemporal dropped on stores (partial-line writeback
// suspect: WRITE_SIZE 172 vs 134 MB ideal). Everything else = R5.

#define B_ 16
#define C_ 128
#define N_ 16384

typedef short bf16x8 __attribute__((ext_vector_type(8)));
typedef float f32x4 __attribute__((ext_vector_type(4)));
typedef unsigned u32x2 __attribute__((ext_vector_type(2)));

__device__ __forceinline__ ushort f2bf(float f) {
    union { float f; unsigned u; } v; v.f = f;
    unsigned r = (v.u + 0x7FFFu + ((v.u >> 16) & 1u)) >> 16;
    return (ushort)r;
}

// ---------------- K0: pack qkv_w fp32 -> bf16 ----------------
__global__ void k_pack(const float* __restrict__ w, ushort* __restrict__ wbf, int n) {
    int i = blockIdx.x * 256 + threadIdx.x;
    if (i < n) wbf[i] = f2bf(w[i]);
}

// ---------------- K1: GroupNorm stats -> folded per-(b,c) scale/bias ----------------
__global__ void k_stats(const float* __restrict__ x, const float* __restrict__ gnw,
                        const float* __restrict__ gnb, float* __restrict__ sc,
                        float* __restrict__ bi) {
    int bg = blockIdx.x;  // b*32+g ; group data contiguous: 4*N_ floats
    const float4* p = (const float4*)(x + (size_t)bg * (4 * N_));
    float s = 0.f, s2 = 0.f;
    for (int i = threadIdx.x; i < N_; i += 1024) {
        float4 v = p[i];
        s  += v.x + v.y + v.z + v.w;
        s2 += v.x * v.x + v.y * v.y + v.z * v.z + v.w * v.w;
    }
    #pragma unroll
    for (int d = 32; d > 0; d >>= 1) { s += __shfl_xor(s, d); s2 += __shfl_xor(s2, d); }
    __shared__ float ls[16], ls2[16];
    int wid = threadIdx.x >> 6, lane = threadIdx.x & 63;
    if (lane == 0) { ls[wid] = s; ls2[wid] = s2; }
    __syncthreads();
    if (threadIdx.x == 0) {
        float S = 0.f, S2 = 0.f;
        #pragma unroll
        for (int i = 0; i < 16; ++i) { S += ls[i]; S2 += ls2[i]; }
        float m = S / 65536.f;
        float var = S2 / 65536.f - m * m;
        float rs = rsqrtf(var + 1e-5f);
        int b = bg >> 5, g = bg & 31;
        #pragma unroll
        for (int i = 0; i < 4; ++i) {
            int c = g * 4 + i;
            float scv = rs * gnw[c];
            sc[b * 128 + c] = scv;
            bi[b * 128 + c] = gnb[c] - m * scv;
        }
    }
}

// ---------------- K2: fused normalize+transpose+qkv+exp(q)+ksm+v+MFMA-ctx ----------
// wave0: q0..q5 | wave1: q6,q7,k(h0),k(h1) | wave2: k(h2),k(h3),v16,v17 | wave3: v18..23

#define MFMA16(A, Bv, Cc) __builtin_amdgcn_mfma_f32_16x16x32_bf16(A, Bv, Cc, 0, 0, 0)

#define DO_Q(J, OT) do { \
    f32x4 acc = {0.f, 0.f, 0.f, 0.f}; \
    acc = MFMA16(wf[J][0], xb[0], acc); acc = MFMA16(wf[J][1], xb[1], acc); \
    acc = MFMA16(wf[J][2], xb[2], acc); acc = MFMA16(wf[J][3], xb[3], acc); \
    float e0 = __expf(acc[0]), e1 = __expf(acc[1]); \
    float e2 = __expf(acc[2]), e3 = __expf(acc[3]); \
    qacc[J][0] += e0; qacc[J][1] += e1; qacc[J][2] += e2; qacc[J][3] += e3; \
    u32x2 pkq; \
    pkq.x = (unsigned)f2bf(e0) | ((unsigned)f2bf(e1) << 16); \
    pkq.y = (unsigned)f2bf(e2) | ((unsigned)f2bf(e3) << 16); \
    *(u32x2*)(eqp + (OT) * 16) = pkq; \
} while (0)

#define DO_K(JLO, H) do { \
    f32x4 aL = {0.f, 0.f, 0.f, 0.f}, aH = {0.f, 0.f, 0.f, 0.f}; \
    aL = MFMA16(wf[JLO][0], xb[0], aL);     aH = MFMA16(wf[(JLO)+1][0], xb[0], aH); \
    aL = MFMA16(wf[JLO][1], xb[1], aL);     aH = MFMA16(wf[(JLO)+1][1], xb[1], aH); \
    aL = MFMA16(wf[JLO][2], xb[2], aL);     aH = MFMA16(wf[(JLO)+1][2], xb[2], aH); \
    aL = MFMA16(wf[JLO][3], xb[3], aL);     aH = MFMA16(wf[(JLO)+1][3], xb[3], aH); \
    float eL0 = __expf(aL[0]), eL1 = __expf(aL[1]), eL2 = __expf(aL[2]), eL3 = __expf(aL[3]); \
    float eH0 = __expf(aH[0]), eH1 = __expf(aH[1]), eH2 = __expf(aH[2]), eH3 = __expf(aH[3]); \
    float s = eL0 + eL1 + eL2 + eL3 + eH0 + eH1 + eH2 + eH3; \
    s += __shfl_xor(s, 16); s += __shfl_xor(s, 32); \
    float rinv = 1.f / s; \
    ksm[H][lg * 4 + 0][nloc] = f2bf(eL0 * rinv); \
    ksm[H][lg * 4 + 1][nloc] = f2bf(eL1 * rinv); \
    ksm[H][lg * 4 + 2][nloc] = f2bf(eL2 * rinv); \
    ksm[H][lg * 4 + 3][nloc] = f2bf(eL3 * rinv); \
    ksm[H][16 + lg * 4 + 0][nloc] = f2bf(eH0 * rinv); \
    ksm[H][16 + lg * 4 + 1][nloc] = f2bf(eH1 * rinv); \
    ksm[H][16 + lg * 4 + 2][nloc] = f2bf(eH2 * rinv); \
    ksm[H][16 + lg * 4 + 3][nloc] = f2bf(eH3 * rinv); \
} while (0)

#define DO_V(J, HV, EB) do { \
    f32x4 acc = {0.f, 0.f, 0.f, 0.f}; \
    acc = MFMA16(wf[J][0], xb[0], acc); acc = MFMA16(wf[J][1], xb[1], acc); \
    acc = MFMA16(wf[J][2], xb[2], acc); acc = MFMA16(wf[J][3], xb[3], acc); \
    vls[HV][(EB) + lg * 4 + 0][nloc] = f2bf(acc[0]); \
    vls[HV][(EB) + lg * 4 + 1][nloc] = f2bf(acc[1]); \
    vls[HV][(EB) + lg * 4 + 2][nloc] = f2bf(acc[2]); \
    vls[HV][(EB) + lg * 4 + 3][nloc] = f2bf(acc[3]); \
} while (0)

__global__ __launch_bounds__(256, 2) void k_main(
    const float* __restrict__ x, const ushort* __restrict__ wbf,
    const float* __restrict__ scA, const float* __restrict__ biA,
    ushort* __restrict__ eqT, float* __restrict__ qsumP, float* __restrict__ ctxP) {
    int blk = blockIdx.x;
    int b = blk >> 6, nb = blk & 63;
    int tid = threadIdx.x, wid = tid >> 6, lane = tid & 63;
    int l15 = lane & 15, lg = lane >> 4;

    // xs: 64 n-rows x 128 c (bf16), row = 256 B, byte col XOR-swizzled by (n&7)<<4
    __shared__ __align__(16) ushort xs[8192];        // 16 KB
    __shared__ __align__(16) ushort ksm[4][32][72];  // [head][d][n(64)+pad]
    __shared__ __align__(16) ushort vls[4][32][72];  // [head][e][n(64)+pad]

    // weight fragments, register-resident for the whole kernel
    bf16x8 wf[6][4];
    {
        const ushort* wr = wbf + (size_t)(wid * 96 + l15) * 128 + lg * 8;
        #pragma unroll
        for (int j = 0; j < 6; ++j)
            #pragma unroll
            for (int kc = 0; kc < 4; ++kc)
                wf[j][kc] = *(const bf16x8*)(wr + j * 2048 + kc * 32);
    }

    float qacc[6][4];
    #pragma unroll
    for (int j = 0; j < 6; ++j)
        #pragma unroll
        for (int r = 0; r < 4; ++r) qacc[j][r] = 0.f;
    f32x4 cacc[2][2];
    #pragma unroll
    for (int di = 0; di < 2; ++di)
        #pragma unroll
        for (int ei = 0; ei < 2; ++ei) cacc[di][ei] = (f32x4){0.f, 0.f, 0.f, 0.f};

    // Phase-A constants: thread (pk_, pcb) loads float4 (n = pk_*4..+3) of
    // channels c = pcb*8..+7, normalizes, register-transposes, b128-writes xs.
    const int pk_ = tid & 15, pcb = tid >> 4;
    const float* xrow = x + (size_t)b * (C_ * N_) + nb * 256 + pk_ * 4;
    float scv[8], biv[8];
    #pragma unroll
    for (int i = 0; i < 8; ++i) {
        scv[i] = scA[b * 128 + pcb * 8 + i];
        biv[i] = biA[b * 128 + pcb * 8 + i];
    }
    unsigned boffj[4];
    #pragma unroll
    for (int j = 0; j < 4; ++j) {
        int n = pk_ * 4 + j;
        boffj[j] = (unsigned)(n * 256 + ((pcb * 16) ^ ((n & 7) << 4)));
    }

    for (int ch = 0; ch < 4; ++ch) {
        // ---- Phase A: x -> normalized bf16 -> xs (swizzled [n][c])
        union { uint4 v; unsigned w[4]; } wj0, wj1, wj2, wj3;
        #pragma unroll
        for (int i = 0; i < 8; ++i) {
            float4 v = *(const float4*)(xrow + (size_t)(pcb * 8 + i) * N_ + ch * 64);
            float s = scv[i], t = biv[i];
            unsigned e0 = f2bf(v.x * s + t), e1 = f2bf(v.y * s + t);
            unsigned e2 = f2bf(v.z * s + t), e3 = f2bf(v.w * s + t);
            int wI = i >> 1;
            if (i & 1) {
                wj0.w[wI] |= e0 << 16; wj1.w[wI] |= e1 << 16;
                wj2.w[wI] |= e2 << 16; wj3.w[wI] |= e3 << 16;
            } else {
                wj0.w[wI] = e0; wj1.w[wI] = e1; wj2.w[wI] = e2; wj3.w[wI] = e3;
            }
        }
        *(uint4*)((char*)xs + boffj[0]) = wj0.v;
        *(uint4*)((char*)xs + boffj[1]) = wj1.v;
        *(uint4*)((char*)xs + boffj[2]) = wj2.v;
        *(uint4*)((char*)xs + boffj[3]) = wj3.v;
        __syncthreads();

        // ---- Phase B: per 16-n tile, xb fragments via swizzled b128 reads
        for (int nt = 0; nt < 4; ++nt) {
            int row = nt * 16 + l15;
            bf16x8 xb[4];
            #pragma unroll
            for (int kc = 0; kc < 4; ++kc) {
                unsigned off = (unsigned)(row * 256 +
                    (((kc * 4 + lg) * 16) ^ ((row & 7) << 4)));
                xb[kc] = *(const bf16x8*)((const char*)xs + off);
            }
            int nloc = nt * 16 + l15;
            int ng = nb * 256 + ch * 64 + nloc;
            ushort* eqp = eqT + ((size_t)b * N_ + ng) * 128 + lg * 4;

            if (wid == 0) {
                DO_Q(0, 0); DO_Q(1, 1); DO_Q(2, 2); DO_Q(3, 3); DO_Q(4, 4); DO_Q(5, 5);
            } else if (wid == 1) {
                DO_Q(0, 6); DO_Q(1, 7); DO_K(2, 0); DO_K(4, 1);
            } else if (wid == 2) {
                DO_K(0, 2); DO_K(2, 3); DO_V(4, 0, 0); DO_V(5, 0, 16);
            } else {
                DO_V(0, 1, 0); DO_V(1, 1, 16); DO_V(2, 2, 0);
                DO_V(3, 2, 16); DO_V(4, 3, 0); DO_V(5, 3, 16);
            }
        }
        __syncthreads();

        // ---- Phase C: ctx[d][e] += ksm . vls^T over this chunk's 64 n (MFMA)
        #pragma unroll
        for (int ks = 0; ks < 2; ++ks) {
            bf16x8 A0 = *(const bf16x8*)&ksm[wid][l15][ks * 32 + lg * 8];
            bf16x8 A1 = *(const bf16x8*)&ksm[wid][16 + l15][ks * 32 + lg * 8];
            bf16x8 B0 = *(const bf16x8*)&vls[wid][l15][ks * 32 + lg * 8];
            bf16x8 B1 = *(const bf16x8*)&vls[wid][16 + l15][ks * 32 + lg * 8];
            cacc[0][0] = MFMA16(A0, B0, cacc[0][0]);
            cacc[0][1] = MFMA16(A0, B1, cacc[0][1]);
            cacc[1][0] = MFMA16(A1, B0, cacc[1][0]);
            cacc[1][1] = MFMA16(A1, B1, cacc[1][1]);
        }
        __syncthreads();
    }

    // ---- qsum: reduce register accumulators over the 16 n-columns (l15 lanes)
    int nq = (wid == 0) ? 6 : (wid == 1 ? 2 : 0);
    #pragma unroll
    for (int j = 0; j < 6; ++j) {
        if (j < nq) {
            #pragma unroll
            for (int r = 0; r < 4; ++r) {
                float s = qacc[j][r];
                s += __shfl_xor(s, 1); s += __shfl_xor(s, 2);
                s += __shfl_xor(s, 4); s += __shfl_xor(s, 8);
                if (l15 == 0)
                    qsumP[(size_t)blk * 128 + (wid * 6 + j) * 16 + lg * 4 + r] = s;
            }
        }
    }
    // ---- ctx partials out (head = wid): D layout col=l15(e), row=lg*4+r(d)
    float* cp = ctxP + (size_t)blk * 4096 + wid * 1024;
    #pragma unroll
    for (int di = 0; di < 2; ++di)
        #pragma unroll
        for (int ei = 0; ei < 2; ++ei)
            #pragma unroll
            for (int r = 0; r < 4; ++r)
                cp[(di * 16 + lg * 4 + r) * 32 + ei * 16 + l15] = cacc[di][ei][r];
}

// ---------------- K2.5: reduce ctxP over the 64 n-blocks (into q=0 slice) ----
__global__ void k_red(float* __restrict__ ctxP) {
    int blk = blockIdx.x;  // B*8
    int b = blk >> 3, sl = blk & 7;
    float* base = ctxP + (size_t)b * 64 * 4096;
    #pragma unroll
    for (int r = 0; r < 2; ++r) {
        int i = sl * 512 + r * 256 + threadIdx.x;
        float s = 0.f;
        for (int q = 0; q < 64; ++q) s += base[(size_t)q * 4096 + i];
        base[i] = s;
    }
}

// ---------------- K3: combine partials, build M''[b][c][hd] bf16 ----------------
__global__ void k_comb(const float* __restrict__ ctxP, const float* __restrict__ qsumP,
                       const float* __restrict__ projw, ushort* __restrict__ mpp) {
    int b = blockIdx.x, tid = threadIdx.x;
    __shared__ float ctx[4096];
    __shared__ float qinv[128];
    for (int i = tid; i < 4096; i += 256)
        ctx[i] = ctxP[(size_t)b * 64 * 4096 + i];
    if (tid < 128) {
        float s = 0.f;
        const float* p = qsumP + (size_t)b * 64 * 128 + tid;
        for (int q = 0; q < 64; ++q) s += p[q * 128];
        qinv[tid] = 1.f / s;
    }
    __syncthreads();
    int c = tid >> 1, hd0 = (tid & 1) * 64;
    unsigned ow[32];
    for (int k = 0; k < 64; ++k) {
        int hd = hd0 + k, h = hd >> 5, d = hd & 31;
        const float* pw = projw + c * 128 + h * 32;
        const float* cx = ctx + h * 1024 + d * 32;
        float s = 0.f;
        #pragma unroll 8
        for (int e = 0; e < 32; ++e) s += pw[e] * cx[e];
        s *= qinv[hd];
        ushort bv = f2bf(s);
        if (k & 1) ow[k >> 1] |= ((unsigned)bv) << 16; else ow[k >> 1] = bv;
    }
    ushort* dst = mpp + ((size_t)(b * 128 + c)) * 128 + hd0;
    #pragma unroll
    for (int q = 0; q < 8; ++q) {
        uint4 t; t.x = ow[q * 4]; t.y = ow[q * 4 + 1]; t.z = ow[q * 4 + 2]; t.w = ow[q * 4 + 3];
        ((uint4*)dst)[q] = t;
    }
}

// ---------------- K4: out = expq . M''^T + proj_b + x (64 n per block) ----------------
// Phase-split for MLP: all 8 MFMA accs -> all 8 x loads -> all 8 stores.
__global__ __launch_bounds__(256) void k_final(
    const ushort* __restrict__ eqT, const ushort* __restrict__ mpp,
    const float* __restrict__ projb, const float* __restrict__ x,
    float* __restrict__ out) {
    int blk = blockIdx.x;
    int b = blk >> 8, nb = blk & 255;
    int tid = threadIdx.x, wid = tid >> 6, lane = tid & 63;
    int l15 = lane & 15, lg = lane >> 4;
    int ntb = nb * 64 + wid * 16;
    const ushort* ar = eqT + (size_t)(b * N_ + ntb + l15) * 128;
    bf16x8 af[4];
    #pragma unroll
    for (int kc = 0; kc < 4; ++kc) af[kc] = *(const bf16x8*)(ar + kc * 32 + lg * 8);

    // Phase 1: all 8 c-tile accumulators (mpp is L2-resident)
    f32x4 acc[8];
    #pragma unroll
    for (int ct = 0; ct < 8; ++ct) {
        f32x4 a = {0.f, 0.f, 0.f, 0.f};
        const ushort* br = mpp + (size_t)(b * 128 + ct * 16 + l15) * 128;
        #pragma unroll
        for (int kc = 0; kc < 4; ++kc) {
            bf16x8 bfg = *(const bf16x8*)(br + kc * 32 + lg * 8);
            a = MFMA16(af[kc], bfg, a);
        }
        acc[ct] = a;
    }

    // Phase 2: issue all 8 residual loads (8-deep MLP)
    int nr = ntb + lg * 4;
    size_t off0 = (size_t)(b * C_ + l15) * N_ + nr;
    f32x4 xv[8];
    #pragma unroll
    for (int ct = 0; ct < 8; ++ct)
        xv[ct] = __builtin_nontemporal_load((const f32x4*)(x + off0 + (size_t)ct * 16 * N_));

    // Phase 3: add + store
    #pragma unroll
    for (int ct = 0; ct < 8; ++ct) {
        float pb = projb[ct * 16 + l15];
        f32x4 o4;
        o4[0] = acc[ct][0] + pb + xv[ct][0];
        o4[1] = acc[ct][1] + pb + xv[ct][1];
        o4[2] = acc[ct][2] + pb + xv[ct][2];
        o4[3] = acc[ct][3] + pb + xv[ct][3];
        *(f32x4*)(out + off0 + (size_t)ct * 16 * N_) = o4;
    }
}

extern "C" void kernel_launch(void* const* d_in, const int* in_sizes, int n_in,
                              void* d_out, int out_size, void* d_ws, size_t ws_size,
                              hipStream_t stream) {
    const float* x     = (const float*)d_in[0];
    const float* gnw   = (const float*)d_in[1];
    const float* gnb   = (const float*)d_in[2];
    const float* qkvw  = (const float*)d_in[3];
    const float* projw = (const float*)d_in[4];
    const float* projb = (const float*)d_in[5];
    float* out = (float*)d_out;

    char* ws = (char*)d_ws;
    ushort* wbf   = (ushort*)(ws);                // 98,304 B
    float*  qsumP = (float*)(ws + 102400);        // 524,288 B
    ushort* mpp   = (ushort*)(ws + 626688);       // 524,288 B
    // sc/bi overlap mpp (disjoint lifetimes: k_stats writes, k_main reads,
    // THEN k_comb writes mpp; re-established identically every replay)
    float*  sc    = (float*)(ws + 626688);        // 8,192 B
    float*  bi    = (float*)(ws + 634880);        // 8,192 B
    float*  ctxP  = (float*)(ws + 1150976);       // 16,777,216 B
    ushort* eqT   = (ushort*)(ws + 17928192);     // 67,108,864 B (end: 85,037,056)

    k_pack <<<192,  256,  0, stream>>>(qkvw, wbf, 384 * 128);
    k_stats<<<512,  1024, 0, stream>>>(x, gnw, gnb, sc, bi);
    k_main <<<1024, 256,  0, stream>>>(x, wbf, sc, bi, eqT, qsumP, ctxP);
    k_red  <<<128,  256,  0, stream>>>(ctxP);
    k_comb <<<16,   256,  0, stream>>>(ctxP, qsumP, projw, mpp);
    k_final<<<4096, 256,  0, stream>>>(eqT, mpp, projb, x, out);
}

// Round 7
// 269.967 us; speedup vs baseline: 2.1574x; 1.0416x over previous
//
#include <hip/hip_runtime.h>

// R7: k_final v3 — the 2.3 TB/s plateau was 16 partial-line transactions per
// memory instruction (c-rows 64KB apart, 64B each). New structure: MFMA ->
// bf16 att tile in LDS (XOR-swizzled [c][n]) -> coalesced store phase where
// each wave instruction covers 2 full c-rows x 512B (8 full lines).
// Everything else unchanged from R6.

#define B_ 16
#define C_ 128
#define N_ 16384

typedef short bf16x8 __attribute__((ext_vector_type(8)));
typedef float f32x4 __attribute__((ext_vector_type(4)));
typedef unsigned u32x2 __attribute__((ext_vector_type(2)));

__device__ __forceinline__ ushort f2bf(float f) {
    union { float f; unsigned u; } v; v.f = f;
    unsigned r = (v.u + 0x7FFFu + ((v.u >> 16) & 1u)) >> 16;
    return (ushort)r;
}
__device__ __forceinline__ float bf2f(unsigned h) {
    union { unsigned u; float f; } v; v.u = h << 16;
    return v.f;
}

// ---------------- K0: pack qkv_w fp32 -> bf16 ----------------
__global__ void k_pack(const float* __restrict__ w, ushort* __restrict__ wbf, int n) {
    int i = blockIdx.x * 256 + threadIdx.x;
    if (i < n) wbf[i] = f2bf(w[i]);
}

// ---------------- K1: GroupNorm stats -> folded per-(b,c) scale/bias ----------------
__global__ void k_stats(const float* __restrict__ x, const float* __restrict__ gnw,
                        const float* __restrict__ gnb, float* __restrict__ sc,
                        float* __restrict__ bi) {
    int bg = blockIdx.x;  // b*32+g ; group data contiguous: 4*N_ floats
    const float4* p = (const float4*)(x + (size_t)bg * (4 * N_));
    float s = 0.f, s2 = 0.f;
    for (int i = threadIdx.x; i < N_; i += 1024) {
        float4 v = p[i];
        s  += v.x + v.y + v.z + v.w;
        s2 += v.x * v.x + v.y * v.y + v.z * v.z + v.w * v.w;
    }
    #pragma unroll
    for (int d = 32; d > 0; d >>= 1) { s += __shfl_xor(s, d); s2 += __shfl_xor(s2, d); }
    __shared__ float ls[16], ls2[16];
    int wid = threadIdx.x >> 6, lane = threadIdx.x & 63;
    if (lane == 0) { ls[wid] = s; ls2[wid] = s2; }
    __syncthreads();
    if (threadIdx.x == 0) {
        float S = 0.f, S2 = 0.f;
        #pragma unroll
        for (int i = 0; i < 16; ++i) { S += ls[i]; S2 += ls2[i]; }
        float m = S / 65536.f;
        float var = S2 / 65536.f - m * m;
        float rs = rsqrtf(var + 1e-5f);
        int b = bg >> 5, g = bg & 31;
        #pragma unroll
        for (int i = 0; i < 4; ++i) {
            int c = g * 4 + i;
            float scv = rs * gnw[c];
            sc[b * 128 + c] = scv;
            bi[b * 128 + c] = gnb[c] - m * scv;
        }
    }
}

// ---------------- K2: fused normalize+transpose+qkv+exp(q)+ksm+v+MFMA-ctx ----------
// wave0: q0..q5 | wave1: q6,q7,k(h0),k(h1) | wave2: k(h2),k(h3),v16,v17 | wave3: v18..23

#define MFMA16(A, Bv, Cc) __builtin_amdgcn_mfma_f32_16x16x32_bf16(A, Bv, Cc, 0, 0, 0)

#define DO_Q(J, OT) do { \
    f32x4 acc = {0.f, 0.f, 0.f, 0.f}; \
    acc = MFMA16(wf[J][0], xb[0], acc); acc = MFMA16(wf[J][1], xb[1], acc); \
    acc = MFMA16(wf[J][2], xb[2], acc); acc = MFMA16(wf[J][3], xb[3], acc); \
    float e0 = __expf(acc[0]), e1 = __expf(acc[1]); \
    float e2 = __expf(acc[2]), e3 = __expf(acc[3]); \
    qacc[J][0] += e0; qacc[J][1] += e1; qacc[J][2] += e2; qacc[J][3] += e3; \
    u32x2 pkq; \
    pkq.x = (unsigned)f2bf(e0) | ((unsigned)f2bf(e1) << 16); \
    pkq.y = (unsigned)f2bf(e2) | ((unsigned)f2bf(e3) << 16); \
    *(u32x2*)(eqp + (OT) * 16) = pkq; \
} while (0)

#define DO_K(JLO, H) do { \
    f32x4 aL = {0.f, 0.f, 0.f, 0.f}, aH = {0.f, 0.f, 0.f, 0.f}; \
    aL = MFMA16(wf[JLO][0], xb[0], aL);     aH = MFMA16(wf[(JLO)+1][0], xb[0], aH); \
    aL = MFMA16(wf[JLO][1], xb[1], aL);     aH = MFMA16(wf[(JLO)+1][1], xb[1], aH); \
    aL = MFMA16(wf[JLO][2], xb[2], aL);     aH = MFMA16(wf[(JLO)+1][2], xb[2], aH); \
    aL = MFMA16(wf[JLO][3], xb[3], aL);     aH = MFMA16(wf[(JLO)+1][3], xb[3], aH); \
    float eL0 = __expf(aL[0]), eL1 = __expf(aL[1]), eL2 = __expf(aL[2]), eL3 = __expf(aL[3]); \
    float eH0 = __expf(aH[0]), eH1 = __expf(aH[1]), eH2 = __expf(aH[2]), eH3 = __expf(aH[3]); \
    float s = eL0 + eL1 + eL2 + eL3 + eH0 + eH1 + eH2 + eH3; \
    s += __shfl_xor(s, 16); s += __shfl_xor(s, 32); \
    float rinv = 1.f / s; \
    ksm[H][lg * 4 + 0][nloc] = f2bf(eL0 * rinv); \
    ksm[H][lg * 4 + 1][nloc] = f2bf(eL1 * rinv); \
    ksm[H][lg * 4 + 2][nloc] = f2bf(eL2 * rinv); \
    ksm[H][lg * 4 + 3][nloc] = f2bf(eL3 * rinv); \
    ksm[H][16 + lg * 4 + 0][nloc] = f2bf(eH0 * rinv); \
    ksm[H][16 + lg * 4 + 1][nloc] = f2bf(eH1 * rinv); \
    ksm[H][16 + lg * 4 + 2][nloc] = f2bf(eH2 * rinv); \
    ksm[H][16 + lg * 4 + 3][nloc] = f2bf(eH3 * rinv); \
} while (0)

#define DO_V(J, HV, EB) do { \
    f32x4 acc = {0.f, 0.f, 0.f, 0.f}; \
    acc = MFMA16(wf[J][0], xb[0], acc); acc = MFMA16(wf[J][1], xb[1], acc); \
    acc = MFMA16(wf[J][2], xb[2], acc); acc = MFMA16(wf[J][3], xb[3], acc); \
    vls[HV][(EB) + lg * 4 + 0][nloc] = f2bf(acc[0]); \
    vls[HV][(EB) + lg * 4 + 1][nloc] = f2bf(acc[1]); \
    vls[HV][(EB) + lg * 4 + 2][nloc] = f2bf(acc[2]); \
    vls[HV][(EB) + lg * 4 + 3][nloc] = f2bf(acc[3]); \
} while (0)

__global__ __launch_bounds__(256, 2) void k_main(
    const float* __restrict__ x, const ushort* __restrict__ wbf,
    const float* __restrict__ scA, const float* __restrict__ biA,
    ushort* __restrict__ eqT, float* __restrict__ qsumP, float* __restrict__ ctxP) {
    int blk = blockIdx.x;
    int b = blk >> 6, nb = blk & 63;
    int tid = threadIdx.x, wid = tid >> 6, lane = tid & 63;
    int l15 = lane & 15, lg = lane >> 4;

    // xs: 64 n-rows x 128 c (bf16), row = 256 B, byte col XOR-swizzled by (n&7)<<4
    __shared__ __align__(16) ushort xs[8192];        // 16 KB
    __shared__ __align__(16) ushort ksm[4][32][72];  // [head][d][n(64)+pad]
    __shared__ __align__(16) ushort vls[4][32][72];  // [head][e][n(64)+pad]

    // weight fragments, register-resident for the whole kernel
    bf16x8 wf[6][4];
    {
        const ushort* wr = wbf + (size_t)(wid * 96 + l15) * 128 + lg * 8;
        #pragma unroll
        for (int j = 0; j < 6; ++j)
            #pragma unroll
            for (int kc = 0; kc < 4; ++kc)
                wf[j][kc] = *(const bf16x8*)(wr + j * 2048 + kc * 32);
    }

    float qacc[6][4];
    #pragma unroll
    for (int j = 0; j < 6; ++j)
        #pragma unroll
        for (int r = 0; r < 4; ++r) qacc[j][r] = 0.f;
    f32x4 cacc[2][2];
    #pragma unroll
    for (int di = 0; di < 2; ++di)
        #pragma unroll
        for (int ei = 0; ei < 2; ++ei) cacc[di][ei] = (f32x4){0.f, 0.f, 0.f, 0.f};

    // Phase-A constants: thread (pk_, pcb) loads float4 (n = pk_*4..+3) of
    // channels c = pcb*8..+7, normalizes, register-transposes, b128-writes xs.
    const int pk_ = tid & 15, pcb = tid >> 4;
    const float* xrow = x + (size_t)b * (C_ * N_) + nb * 256 + pk_ * 4;
    float scv[8], biv[8];
    #pragma unroll
    for (int i = 0; i < 8; ++i) {
        scv[i] = scA[b * 128 + pcb * 8 + i];
        biv[i] = biA[b * 128 + pcb * 8 + i];
    }
    unsigned boffj[4];
    #pragma unroll
    for (int j = 0; j < 4; ++j) {
        int n = pk_ * 4 + j;
        boffj[j] = (unsigned)(n * 256 + ((pcb * 16) ^ ((n & 7) << 4)));
    }

    for (int ch = 0; ch < 4; ++ch) {
        // ---- Phase A: x -> normalized bf16 -> xs (swizzled [n][c])
        union { uint4 v; unsigned w[4]; } wj0, wj1, wj2, wj3;
        #pragma unroll
        for (int i = 0; i < 8; ++i) {
            float4 v = *(const float4*)(xrow + (size_t)(pcb * 8 + i) * N_ + ch * 64);
            float s = scv[i], t = biv[i];
            unsigned e0 = f2bf(v.x * s + t), e1 = f2bf(v.y * s + t);
            unsigned e2 = f2bf(v.z * s + t), e3 = f2bf(v.w * s + t);
            int wI = i >> 1;
            if (i & 1) {
                wj0.w[wI] |= e0 << 16; wj1.w[wI] |= e1 << 16;
                wj2.w[wI] |= e2 << 16; wj3.w[wI] |= e3 << 16;
            } else {
                wj0.w[wI] = e0; wj1.w[wI] = e1; wj2.w[wI] = e2; wj3.w[wI] = e3;
            }
        }
        *(uint4*)((char*)xs + boffj[0]) = wj0.v;
        *(uint4*)((char*)xs + boffj[1]) = wj1.v;
        *(uint4*)((char*)xs + boffj[2]) = wj2.v;
        *(uint4*)((char*)xs + boffj[3]) = wj3.v;
        __syncthreads();

        // ---- Phase B: per 16-n tile, xb fragments via swizzled b128 reads
        for (int nt = 0; nt < 4; ++nt) {
            int row = nt * 16 + l15;
            bf16x8 xb[4];
            #pragma unroll
            for (int kc = 0; kc < 4; ++kc) {
                unsigned off = (unsigned)(row * 256 +
                    (((kc * 4 + lg) * 16) ^ ((row & 7) << 4)));
                xb[kc] = *(const bf16x8*)((const char*)xs + off);
            }
            int nloc = nt * 16 + l15;
            int ng = nb * 256 + ch * 64 + nloc;
            ushort* eqp = eqT + ((size_t)b * N_ + ng) * 128 + lg * 4;

            if (wid == 0) {
                DO_Q(0, 0); DO_Q(1, 1); DO_Q(2, 2); DO_Q(3, 3); DO_Q(4, 4); DO_Q(5, 5);
            } else if (wid == 1) {
                DO_Q(0, 6); DO_Q(1, 7); DO_K(2, 0); DO_K(4, 1);
            } else if (wid == 2) {
                DO_K(0, 2); DO_K(2, 3); DO_V(4, 0, 0); DO_V(5, 0, 16);
            } else {
                DO_V(0, 1, 0); DO_V(1, 1, 16); DO_V(2, 2, 0);
                DO_V(3, 2, 16); DO_V(4, 3, 0); DO_V(5, 3, 16);
            }
        }
        __syncthreads();

        // ---- Phase C: ctx[d][e] += ksm . vls^T over this chunk's 64 n (MFMA)
        #pragma unroll
        for (int ks = 0; ks < 2; ++ks) {
            bf16x8 A0 = *(const bf16x8*)&ksm[wid][l15][ks * 32 + lg * 8];
            bf16x8 A1 = *(const bf16x8*)&ksm[wid][16 + l15][ks * 32 + lg * 8];
            bf16x8 B0 = *(const bf16x8*)&vls[wid][l15][ks * 32 + lg * 8];
            bf16x8 B1 = *(const bf16x8*)&vls[wid][16 + l15][ks * 32 + lg * 8];
            cacc[0][0] = MFMA16(A0, B0, cacc[0][0]);
            cacc[0][1] = MFMA16(A0, B1, cacc[0][1]);
            cacc[1][0] = MFMA16(A1, B0, cacc[1][0]);
            cacc[1][1] = MFMA16(A1, B1, cacc[1][1]);
        }
        __syncthreads();
    }

    // ---- qsum: reduce register accumulators over the 16 n-columns (l15 lanes)
    int nq = (wid == 0) ? 6 : (wid == 1 ? 2 : 0);
    #pragma unroll
    for (int j = 0; j < 6; ++j) {
        if (j < nq) {
            #pragma unroll
            for (int r = 0; r < 4; ++r) {
                float s = qacc[j][r];
                s += __shfl_xor(s, 1); s += __shfl_xor(s, 2);
                s += __shfl_xor(s, 4); s += __shfl_xor(s, 8);
                if (l15 == 0)
                    qsumP[(size_t)blk * 128 + (wid * 6 + j) * 16 + lg * 4 + r] = s;
            }
        }
    }
    // ---- ctx partials out (head = wid): D layout col=l15(e), row=lg*4+r(d)
    float* cp = ctxP + (size_t)blk * 4096 + wid * 1024;
    #pragma unroll
    for (int di = 0; di < 2; ++di)
        #pragma unroll
        for (int ei = 0; ei < 2; ++ei)
            #pragma unroll
            for (int r = 0; r < 4; ++r)
                cp[(di * 16 + lg * 4 + r) * 32 + ei * 16 + l15] = cacc[di][ei][r];
}

// ---------------- K2.5: reduce ctxP over the 64 n-blocks (into q=0 slice) ----
__global__ void k_red(float* __restrict__ ctxP) {
    int blk = blockIdx.x;  // B*8
    int b = blk >> 3, sl = blk & 7;
    float* base = ctxP + (size_t)b * 64 * 4096;
    #pragma unroll
    for (int r = 0; r < 2; ++r) {
        int i = sl * 512 + r * 256 + threadIdx.x;
        float s = 0.f;
        for (int q = 0; q < 64; ++q) s += base[(size_t)q * 4096 + i];
        base[i] = s;
    }
}

// ---------------- K3: combine partials, build M''[b][c][hd] bf16 ----------------
__global__ void k_comb(const float* __restrict__ ctxP, const float* __restrict__ qsumP,
                       const float* __restrict__ projw, ushort* __restrict__ mpp) {
    int b = blockIdx.x, tid = threadIdx.x;
    __shared__ float ctx[4096];
    __shared__ float qinv[128];
    for (int i = tid; i < 4096; i += 256)
        ctx[i] = ctxP[(size_t)b * 64 * 4096 + i];
    if (tid < 128) {
        float s = 0.f;
        const float* p = qsumP + (size_t)b * 64 * 128 + tid;
        for (int q = 0; q < 64; ++q) s += p[q * 128];
        qinv[tid] = 1.f / s;
    }
    __syncthreads();
    int c = tid >> 1, hd0 = (tid & 1) * 64;
    unsigned ow[32];
    for (int k = 0; k < 64; ++k) {
        int hd = hd0 + k, h = hd >> 5, d = hd & 31;
        const float* pw = projw + c * 128 + h * 32;
        const float* cx = ctx + h * 1024 + d * 32;
        float s = 0.f;
        #pragma unroll 8
        for (int e = 0; e < 32; ++e) s += pw[e] * cx[e];
        s *= qinv[hd];
        ushort bv = f2bf(s);
        if (k & 1) ow[k >> 1] |= ((unsigned)bv) << 16; else ow[k >> 1] = bv;
    }
    ushort* dst = mpp + ((size_t)(b * 128 + c)) * 128 + hd0;
    #pragma unroll
    for (int q = 0; q < 8; ++q) {
        uint4 t; t.x = ow[q * 4]; t.y = ow[q * 4 + 1]; t.z = ow[q * 4 + 2]; t.w = ow[q * 4 + 3];
        ((uint4*)dst)[q] = t;
    }
}

// ---------------- K4: out = expq . M''^T + proj_b + x ----------------
// Block = 256 n x 128 c, two 128-n rounds. Round: MFMA (D col=c,row=n) ->
// bf16 att[c][n128] in LDS (XOR-swizzled) -> coalesced read-back + residual
// + store (each wave instr = 2 full c-rows x 512B = 8 full 128B lines).
__global__ __launch_bounds__(256) void k_final(
    const ushort* __restrict__ eqT, const ushort* __restrict__ mpp,
    const float* __restrict__ projb, const float* __restrict__ x,
    float* __restrict__ out) {
    int blk = blockIdx.x;
    int b = blk >> 6, nb = blk & 63;
    int tid = threadIdx.x, wid = tid >> 6, lane = tid & 63;
    int l15 = lane & 15, lg = lane >> 4;

    __shared__ __align__(16) ushort att[16384];  // 32 KB: [c 128][n 128] bf16 swizzled

    // mpp fragments (B operand): wave owns ct = wid*2, wid*2+1  (c rows wid*32..+31)
    bf16x8 bm[2][4];
    #pragma unroll
    for (int ctk = 0; ctk < 2; ++ctk) {
        const ushort* br = mpp + ((size_t)(b * 128 + (wid * 2 + ctk) * 16 + l15)) * 128 + lg * 8;
        #pragma unroll
        for (int kc = 0; kc < 4; ++kc) bm[ctk][kc] = *(const bf16x8*)(br + kc * 32);
    }

    for (int rnd = 0; rnd < 2; ++rnd) {
        int n0 = nb * 256 + rnd * 128;
        // ---- MFMA + stage to LDS
        #pragma unroll
        for (int nt = 0; nt < 8; ++nt) {
            const ushort* ar = eqT + ((size_t)b * N_ + n0 + nt * 16 + l15) * 128 + lg * 8;
            bf16x8 af[4];
            #pragma unroll
            for (int kc = 0; kc < 4; ++kc) af[kc] = *(const bf16x8*)(ar + kc * 32);
            #pragma unroll
            for (int ctk = 0; ctk < 2; ++ctk) {
                f32x4 a = {0.f, 0.f, 0.f, 0.f};
                #pragma unroll
                for (int kc = 0; kc < 4; ++kc) a = MFMA16(af[kc], bm[ctk][kc], a);
                int c = (wid * 2 + ctk) * 16 + l15;
                int nloc = nt * 16 + lg * 4;
                unsigned byte = (unsigned)(c * 256 + ((nloc * 2) ^ ((c & 15) << 4)));
                u32x2 pk;
                pk.x = (unsigned)f2bf(a[0]) | ((unsigned)f2bf(a[1]) << 16);
                pk.y = (unsigned)f2bf(a[2]) | ((unsigned)f2bf(a[3]) << 16);
                *(u32x2*)((char*)att + byte) = pk;
            }
        }
        __syncthreads();

        // ---- read-back + residual + coalesced store
        int crow = lane >> 5;        // 0/1: which of the 2 c-rows this instr covers
        int n4 = (lane & 31) * 4;    // 4 n per lane, 128 n per 32 lanes
        #pragma unroll
        for (int it = 0; it < 16; ++it) {
            int c = wid * 32 + it * 2 + crow;
            unsigned byte = (unsigned)(c * 256 + ((n4 * 2) ^ ((c & 15) << 4)));
            u32x2 pk = *(const u32x2*)((const char*)att + byte);
            size_t off = (size_t)(b * C_ + c) * N_ + n0 + n4;
            f32x4 xv = __builtin_nontemporal_load((const f32x4*)(x + off));
            float pbv = projb[c];
            f32x4 o4;
            o4[0] = bf2f(pk.x & 0xffffu) + pbv + xv[0];
            o4[1] = bf2f(pk.x >> 16)     + pbv + xv[1];
            o4[2] = bf2f(pk.y & 0xffffu) + pbv + xv[2];
            o4[3] = bf2f(pk.y >> 16)     + pbv + xv[3];
            *(f32x4*)(out + off) = o4;
        }
        __syncthreads();
    }
}

extern "C" void kernel_launch(void* const* d_in, const int* in_sizes, int n_in,
                              void* d_out, int out_size, void* d_ws, size_t ws_size,
                              hipStream_t stream) {
    const float* x     = (const float*)d_in[0];
    const float* gnw   = (const float*)d_in[1];
    const float* gnb   = (const float*)d_in[2];
    const float* qkvw  = (const float*)d_in[3];
    const float* projw = (const float*)d_in[4];
    const float* projb = (const float*)d_in[5];
    float* out = (float*)d_out;

    char* ws = (char*)d_ws;
    ushort* wbf   = (ushort*)(ws);                // 98,304 B
    float*  qsumP = (float*)(ws + 102400);        // 524,288 B
    ushort* mpp   = (ushort*)(ws + 626688);       // 524,288 B
    // sc/bi overlap mpp (disjoint lifetimes: k_stats writes, k_main reads,
    // THEN k_comb writes mpp; re-established identically every replay)
    float*  sc    = (float*)(ws + 626688);        // 8,192 B
    float*  bi    = (float*)(ws + 634880);        // 8,192 B
    float*  ctxP  = (float*)(ws + 1150976);       // 16,777,216 B
    ushort* eqT   = (ushort*)(ws + 17928192);     // 67,108,864 B (end: 85,037,056)

    k_pack <<<192,  256,  0, stream>>>(qkvw, wbf, 384 * 128);
    k_stats<<<512,  1024, 0, stream>>>(x, gnw, gnb, sc, bi);
    k_main <<<1024, 256,  0, stream>>>(x, wbf, sc, bi, eqT, qsumP, ctxP);
    k_red  <<<128,  256,  0, stream>>>(ctxP);
    k_comb <<<16,   256,  0, stream>>>(ctxP, qsumP, projw, mpp);
    k_final<<<1024, 256,  0, stream>>>(eqT, mpp, projb, x, out);
}

// Round 8
// 241.270 us; speedup vs baseline: 2.4140x; 1.1189x over previous
//
#include <hip/hip_runtime.h>

// R8: k_final regrid 1024x(256n,2 rounds) -> 2048x(128n,1 round), trailing
// barrier dropped. Theory: 2.4 TB/s plateau = phase-burst serialization at
// 4 blocks/CU; more phase-staggered block contexts -> continuous issue.
// Everything else identical to R7.

#define B_ 16
#define C_ 128
#define N_ 16384

typedef short bf16x8 __attribute__((ext_vector_type(8)));
typedef float f32x4 __attribute__((ext_vector_type(4)));
typedef unsigned u32x2 __attribute__((ext_vector_type(2)));

__device__ __forceinline__ ushort f2bf(float f) {
    union { float f; unsigned u; } v; v.f = f;
    unsigned r = (v.u + 0x7FFFu + ((v.u >> 16) & 1u)) >> 16;
    return (ushort)r;
}
__device__ __forceinline__ float bf2f(unsigned h) {
    union { unsigned u; float f; } v; v.u = h << 16;
    return v.f;
}

// ---------------- K0: pack qkv_w fp32 -> bf16 ----------------
__global__ void k_pack(const float* __restrict__ w, ushort* __restrict__ wbf, int n) {
    int i = blockIdx.x * 256 + threadIdx.x;
    if (i < n) wbf[i] = f2bf(w[i]);
}

// ---------------- K1: GroupNorm stats -> folded per-(b,c) scale/bias ----------------
__global__ void k_stats(const float* __restrict__ x, const float* __restrict__ gnw,
                        const float* __restrict__ gnb, float* __restrict__ sc,
                        float* __restrict__ bi) {
    int bg = blockIdx.x;  // b*32+g ; group data contiguous: 4*N_ floats
    const float4* p = (const float4*)(x + (size_t)bg * (4 * N_));
    float s = 0.f, s2 = 0.f;
    for (int i = threadIdx.x; i < N_; i += 1024) {
        float4 v = p[i];
        s  += v.x + v.y + v.z + v.w;
        s2 += v.x * v.x + v.y * v.y + v.z * v.z + v.w * v.w;
    }
    #pragma unroll
    for (int d = 32; d > 0; d >>= 1) { s += __shfl_xor(s, d); s2 += __shfl_xor(s2, d); }
    __shared__ float ls[16], ls2[16];
    int wid = threadIdx.x >> 6, lane = threadIdx.x & 63;
    if (lane == 0) { ls[wid] = s; ls2[wid] = s2; }
    __syncthreads();
    if (threadIdx.x == 0) {
        float S = 0.f, S2 = 0.f;
        #pragma unroll
        for (int i = 0; i < 16; ++i) { S += ls[i]; S2 += ls2[i]; }
        float m = S / 65536.f;
        float var = S2 / 65536.f - m * m;
        float rs = rsqrtf(var + 1e-5f);
        int b = bg >> 5, g = bg & 31;
        #pragma unroll
        for (int i = 0; i < 4; ++i) {
            int c = g * 4 + i;
            float scv = rs * gnw[c];
            sc[b * 128 + c] = scv;
            bi[b * 128 + c] = gnb[c] - m * scv;
        }
    }
}

// ---------------- K2: fused normalize+transpose+qkv+exp(q)+ksm+v+MFMA-ctx ----------
// wave0: q0..q5 | wave1: q6,q7,k(h0),k(h1) | wave2: k(h2),k(h3),v16,v17 | wave3: v18..23

#define MFMA16(A, Bv, Cc) __builtin_amdgcn_mfma_f32_16x16x32_bf16(A, Bv, Cc, 0, 0, 0)

#define DO_Q(J, OT) do { \
    f32x4 acc = {0.f, 0.f, 0.f, 0.f}; \
    acc = MFMA16(wf[J][0], xb[0], acc); acc = MFMA16(wf[J][1], xb[1], acc); \
    acc = MFMA16(wf[J][2], xb[2], acc); acc = MFMA16(wf[J][3], xb[3], acc); \
    float e0 = __expf(acc[0]), e1 = __expf(acc[1]); \
    float e2 = __expf(acc[2]), e3 = __expf(acc[3]); \
    qacc[J][0] += e0; qacc[J][1] += e1; qacc[J][2] += e2; qacc[J][3] += e3; \
    u32x2 pkq; \
    pkq.x = (unsigned)f2bf(e0) | ((unsigned)f2bf(e1) << 16); \
    pkq.y = (unsigned)f2bf(e2) | ((unsigned)f2bf(e3) << 16); \
    *(u32x2*)(eqp + (OT) * 16) = pkq; \
} while (0)

#define DO_K(JLO, H) do { \
    f32x4 aL = {0.f, 0.f, 0.f, 0.f}, aH = {0.f, 0.f, 0.f, 0.f}; \
    aL = MFMA16(wf[JLO][0], xb[0], aL);     aH = MFMA16(wf[(JLO)+1][0], xb[0], aH); \
    aL = MFMA16(wf[JLO][1], xb[1], aL);     aH = MFMA16(wf[(JLO)+1][1], xb[1], aH); \
    aL = MFMA16(wf[JLO][2], xb[2], aL);     aH = MFMA16(wf[(JLO)+1][2], xb[2], aH); \
    aL = MFMA16(wf[JLO][3], xb[3], aL);     aH = MFMA16(wf[(JLO)+1][3], xb[3], aH); \
    float eL0 = __expf(aL[0]), eL1 = __expf(aL[1]), eL2 = __expf(aL[2]), eL3 = __expf(aL[3]); \
    float eH0 = __expf(aH[0]), eH1 = __expf(aH[1]), eH2 = __expf(aH[2]), eH3 = __expf(aH[3]); \
    float s = eL0 + eL1 + eL2 + eL3 + eH0 + eH1 + eH2 + eH3; \
    s += __shfl_xor(s, 16); s += __shfl_xor(s, 32); \
    float rinv = 1.f / s; \
    ksm[H][lg * 4 + 0][nloc] = f2bf(eL0 * rinv); \
    ksm[H][lg * 4 + 1][nloc] = f2bf(eL1 * rinv); \
    ksm[H][lg * 4 + 2][nloc] = f2bf(eL2 * rinv); \
    ksm[H][lg * 4 + 3][nloc] = f2bf(eL3 * rinv); \
    ksm[H][16 + lg * 4 + 0][nloc] = f2bf(eH0 * rinv); \
    ksm[H][16 + lg * 4 + 1][nloc] = f2bf(eH1 * rinv); \
    ksm[H][16 + lg * 4 + 2][nloc] = f2bf(eH2 * rinv); \
    ksm[H][16 + lg * 4 + 3][nloc] = f2bf(eH3 * rinv); \
} while (0)

#define DO_V(J, HV, EB) do { \
    f32x4 acc = {0.f, 0.f, 0.f, 0.f}; \
    acc = MFMA16(wf[J][0], xb[0], acc); acc = MFMA16(wf[J][1], xb[1], acc); \
    acc = MFMA16(wf[J][2], xb[2], acc); acc = MFMA16(wf[J][3], xb[3], acc); \
    vls[HV][(EB) + lg * 4 + 0][nloc] = f2bf(acc[0]); \
    vls[HV][(EB) + lg * 4 + 1][nloc] = f2bf(acc[1]); \
    vls[HV][(EB) + lg * 4 + 2][nloc] = f2bf(acc[2]); \
    vls[HV][(EB) + lg * 4 + 3][nloc] = f2bf(acc[3]); \
} while (0)

__global__ __launch_bounds__(256, 2) void k_main(
    const float* __restrict__ x, const ushort* __restrict__ wbf,
    const float* __restrict__ scA, const float* __restrict__ biA,
    ushort* __restrict__ eqT, float* __restrict__ qsumP, float* __restrict__ ctxP) {
    int blk = blockIdx.x;
    int b = blk >> 6, nb = blk & 63;
    int tid = threadIdx.x, wid = tid >> 6, lane = tid & 63;
    int l15 = lane & 15, lg = lane >> 4;

    // xs: 64 n-rows x 128 c (bf16), row = 256 B, byte col XOR-swizzled by (n&7)<<4
    __shared__ __align__(16) ushort xs[8192];        // 16 KB
    __shared__ __align__(16) ushort ksm[4][32][72];  // [head][d][n(64)+pad]
    __shared__ __align__(16) ushort vls[4][32][72];  // [head][e][n(64)+pad]

    // weight fragments, register-resident for the whole kernel
    bf16x8 wf[6][4];
    {
        const ushort* wr = wbf + (size_t)(wid * 96 + l15) * 128 + lg * 8;
        #pragma unroll
        for (int j = 0; j < 6; ++j)
            #pragma unroll
            for (int kc = 0; kc < 4; ++kc)
                wf[j][kc] = *(const bf16x8*)(wr + j * 2048 + kc * 32);
    }

    float qacc[6][4];
    #pragma unroll
    for (int j = 0; j < 6; ++j)
        #pragma unroll
        for (int r = 0; r < 4; ++r) qacc[j][r] = 0.f;
    f32x4 cacc[2][2];
    #pragma unroll
    for (int di = 0; di < 2; ++di)
        #pragma unroll
        for (int ei = 0; ei < 2; ++ei) cacc[di][ei] = (f32x4){0.f, 0.f, 0.f, 0.f};

    // Phase-A constants: thread (pk_, pcb) loads float4 (n = pk_*4..+3) of
    // channels c = pcb*8..+7, normalizes, register-transposes, b128-writes xs.
    const int pk_ = tid & 15, pcb = tid >> 4;
    const float* xrow = x + (size_t)b * (C_ * N_) + nb * 256 + pk_ * 4;
    float scv[8], biv[8];
    #pragma unroll
    for (int i = 0; i < 8; ++i) {
        scv[i] = scA[b * 128 + pcb * 8 + i];
        biv[i] = biA[b * 128 + pcb * 8 + i];
    }
    unsigned boffj[4];
    #pragma unroll
    for (int j = 0; j < 4; ++j) {
        int n = pk_ * 4 + j;
        boffj[j] = (unsigned)(n * 256 + ((pcb * 16) ^ ((n & 7) << 4)));
    }

    for (int ch = 0; ch < 4; ++ch) {
        // ---- Phase A: x -> normalized bf16 -> xs (swizzled [n][c])
        union { uint4 v; unsigned w[4]; } wj0, wj1, wj2, wj3;
        #pragma unroll
        for (int i = 0; i < 8; ++i) {
            float4 v = *(const float4*)(xrow + (size_t)(pcb * 8 + i) * N_ + ch * 64);
            float s = scv[i], t = biv[i];
            unsigned e0 = f2bf(v.x * s + t), e1 = f2bf(v.y * s + t);
            unsigned e2 = f2bf(v.z * s + t), e3 = f2bf(v.w * s + t);
            int wI = i >> 1;
            if (i & 1) {
                wj0.w[wI] |= e0 << 16; wj1.w[wI] |= e1 << 16;
                wj2.w[wI] |= e2 << 16; wj3.w[wI] |= e3 << 16;
            } else {
                wj0.w[wI] = e0; wj1.w[wI] = e1; wj2.w[wI] = e2; wj3.w[wI] = e3;
            }
        }
        *(uint4*)((char*)xs + boffj[0]) = wj0.v;
        *(uint4*)((char*)xs + boffj[1]) = wj1.v;
        *(uint4*)((char*)xs + boffj[2]) = wj2.v;
        *(uint4*)((char*)xs + boffj[3]) = wj3.v;
        __syncthreads();

        // ---- Phase B: per 16-n tile, xb fragments via swizzled b128 reads
        for (int nt = 0; nt < 4; ++nt) {
            int row = nt * 16 + l15;
            bf16x8 xb[4];
            #pragma unroll
            for (int kc = 0; kc < 4; ++kc) {
                unsigned off = (unsigned)(row * 256 +
                    (((kc * 4 + lg) * 16) ^ ((row & 7) << 4)));
                xb[kc] = *(const bf16x8*)((const char*)xs + off);
            }
            int nloc = nt * 16 + l15;
            int ng = nb * 256 + ch * 64 + nloc;
            ushort* eqp = eqT + ((size_t)b * N_ + ng) * 128 + lg * 4;

            if (wid == 0) {
                DO_Q(0, 0); DO_Q(1, 1); DO_Q(2, 2); DO_Q(3, 3); DO_Q(4, 4); DO_Q(5, 5);
            } else if (wid == 1) {
                DO_Q(0, 6); DO_Q(1, 7); DO_K(2, 0); DO_K(4, 1);
            } else if (wid == 2) {
                DO_K(0, 2); DO_K(2, 3); DO_V(4, 0, 0); DO_V(5, 0, 16);
            } else {
                DO_V(0, 1, 0); DO_V(1, 1, 16); DO_V(2, 2, 0);
                DO_V(3, 2, 16); DO_V(4, 3, 0); DO_V(5, 3, 16);
            }
        }
        __syncthreads();

        // ---- Phase C: ctx[d][e] += ksm . vls^T over this chunk's 64 n (MFMA)
        #pragma unroll
        for (int ks = 0; ks < 2; ++ks) {
            bf16x8 A0 = *(const bf16x8*)&ksm[wid][l15][ks * 32 + lg * 8];
            bf16x8 A1 = *(const bf16x8*)&ksm[wid][16 + l15][ks * 32 + lg * 8];
            bf16x8 B0 = *(const bf16x8*)&vls[wid][l15][ks * 32 + lg * 8];
            bf16x8 B1 = *(const bf16x8*)&vls[wid][16 + l15][ks * 32 + lg * 8];
            cacc[0][0] = MFMA16(A0, B0, cacc[0][0]);
            cacc[0][1] = MFMA16(A0, B1, cacc[0][1]);
            cacc[1][0] = MFMA16(A1, B0, cacc[1][0]);
            cacc[1][1] = MFMA16(A1, B1, cacc[1][1]);
        }
        __syncthreads();
    }

    // ---- qsum: reduce register accumulators over the 16 n-columns (l15 lanes)
    int nq = (wid == 0) ? 6 : (wid == 1 ? 2 : 0);
    #pragma unroll
    for (int j = 0; j < 6; ++j) {
        if (j < nq) {
            #pragma unroll
            for (int r = 0; r < 4; ++r) {
                float s = qacc[j][r];
                s += __shfl_xor(s, 1); s += __shfl_xor(s, 2);
                s += __shfl_xor(s, 4); s += __shfl_xor(s, 8);
                if (l15 == 0)
                    qsumP[(size_t)blk * 128 + (wid * 6 + j) * 16 + lg * 4 + r] = s;
            }
        }
    }
    // ---- ctx partials out (head = wid): D layout col=l15(e), row=lg*4+r(d)
    float* cp = ctxP + (size_t)blk * 4096 + wid * 1024;
    #pragma unroll
    for (int di = 0; di < 2; ++di)
        #pragma unroll
        for (int ei = 0; ei < 2; ++ei)
            #pragma unroll
            for (int r = 0; r < 4; ++r)
                cp[(di * 16 + lg * 4 + r) * 32 + ei * 16 + l15] = cacc[di][ei][r];
}

// ---------------- K2.5: reduce ctxP over the 64 n-blocks (into q=0 slice) ----
__global__ void k_red(float* __restrict__ ctxP) {
    int blk = blockIdx.x;  // B*8
    int b = blk >> 3, sl = blk & 7;
    float* base = ctxP + (size_t)b * 64 * 4096;
    #pragma unroll
    for (int r = 0; r < 2; ++r) {
        int i = sl * 512 + r * 256 + threadIdx.x;
        float s = 0.f;
        for (int q = 0; q < 64; ++q) s += base[(size_t)q * 4096 + i];
        base[i] = s;
    }
}

// ---------------- K3: combine partials, build M''[b][c][hd] bf16 ----------------
__global__ void k_comb(const float* __restrict__ ctxP, const float* __restrict__ qsumP,
                       const float* __restrict__ projw, ushort* __restrict__ mpp) {
    int b = blockIdx.x, tid = threadIdx.x;
    __shared__ float ctx[4096];
    __shared__ float qinv[128];
    for (int i = tid; i < 4096; i += 256)
        ctx[i] = ctxP[(size_t)b * 64 * 4096 + i];
    if (tid < 128) {
        float s = 0.f;
        const float* p = qsumP + (size_t)b * 64 * 128 + tid;
        for (int q = 0; q < 64; ++q) s += p[q * 128];
        qinv[tid] = 1.f / s;
    }
    __syncthreads();
    int c = tid >> 1, hd0 = (tid & 1) * 64;
    unsigned ow[32];
    for (int k = 0; k < 64; ++k) {
        int hd = hd0 + k, h = hd >> 5, d = hd & 31;
        const float* pw = projw + c * 128 + h * 32;
        const float* cx = ctx + h * 1024 + d * 32;
        float s = 0.f;
        #pragma unroll 8
        for (int e = 0; e < 32; ++e) s += pw[e] * cx[e];
        s *= qinv[hd];
        ushort bv = f2bf(s);
        if (k & 1) ow[k >> 1] |= ((unsigned)bv) << 16; else ow[k >> 1] = bv;
    }
    ushort* dst = mpp + ((size_t)(b * 128 + c)) * 128 + hd0;
    #pragma unroll
    for (int q = 0; q < 8; ++q) {
        uint4 t; t.x = ow[q * 4]; t.y = ow[q * 4 + 1]; t.z = ow[q * 4 + 2]; t.w = ow[q * 4 + 3];
        ((uint4*)dst)[q] = t;
    }
}

// ---------------- K4: out = expq . M''^T + proj_b + x ----------------
// Block = 128 n x 128 c, ONE round: MFMA (D col=c,row=n) -> bf16 att[c][n]
// LDS (XOR-swizzled) -> barrier -> coalesced read-back + residual + store.
// 2048 blocks for phase-staggered concurrency; no trailing barrier.
__global__ __launch_bounds__(256) void k_final(
    const ushort* __restrict__ eqT, const ushort* __restrict__ mpp,
    const float* __restrict__ projb, const float* __restrict__ x,
    float* __restrict__ out) {
    int blk = blockIdx.x;
    int b = blk >> 7, nb = blk & 127;
    int tid = threadIdx.x, wid = tid >> 6, lane = tid & 63;
    int l15 = lane & 15, lg = lane >> 4;

    __shared__ __align__(16) ushort att[16384];  // 32 KB: [c 128][n 128] bf16 swizzled

    // mpp fragments (B operand): wave owns ct = wid*2, wid*2+1  (c rows wid*32..+31)
    bf16x8 bm[2][4];
    #pragma unroll
    for (int ctk = 0; ctk < 2; ++ctk) {
        const ushort* br = mpp + ((size_t)(b * 128 + (wid * 2 + ctk) * 16 + l15)) * 128 + lg * 8;
        #pragma unroll
        for (int kc = 0; kc < 4; ++kc) bm[ctk][kc] = *(const bf16x8*)(br + kc * 32);
    }

    int n0 = nb * 128;
    // ---- MFMA + stage to LDS
    #pragma unroll
    for (int nt = 0; nt < 8; ++nt) {
        const ushort* ar = eqT + ((size_t)b * N_ + n0 + nt * 16 + l15) * 128 + lg * 8;
        bf16x8 af[4];
        #pragma unroll
        for (int kc = 0; kc < 4; ++kc) af[kc] = *(const bf16x8*)(ar + kc * 32);
        #pragma unroll
        for (int ctk = 0; ctk < 2; ++ctk) {
            f32x4 a = {0.f, 0.f, 0.f, 0.f};
            #pragma unroll
            for (int kc = 0; kc < 4; ++kc) a = MFMA16(af[kc], bm[ctk][kc], a);
            int c = (wid * 2 + ctk) * 16 + l15;
            int nloc = nt * 16 + lg * 4;
            unsigned byte = (unsigned)(c * 256 + ((nloc * 2) ^ ((c & 15) << 4)));
            u32x2 pk;
            pk.x = (unsigned)f2bf(a[0]) | ((unsigned)f2bf(a[1]) << 16);
            pk.y = (unsigned)f2bf(a[2]) | ((unsigned)f2bf(a[3]) << 16);
            *(u32x2*)((char*)att + byte) = pk;
        }
    }
    __syncthreads();

    // ---- read-back + residual + coalesced store
    int crow = lane >> 5;        // 0/1: which of the 2 c-rows this instr covers
    int n4 = (lane & 31) * 4;    // 4 n per lane, 128 n per 32 lanes
    #pragma unroll
    for (int it = 0; it < 16; ++it) {
        int c = wid * 32 + it * 2 + crow;
        unsigned byte = (unsigned)(c * 256 + ((n4 * 2) ^ ((c & 15) << 4)));
        u32x2 pk = *(const u32x2*)((const char*)att + byte);
        size_t off = (size_t)(b * C_ + c) * N_ + n0 + n4;
        f32x4 xv = __builtin_nontemporal_load((const f32x4*)(x + off));
        float pbv = projb[c];
        f32x4 o4;
        o4[0] = bf2f(pk.x & 0xffffu) + pbv + xv[0];
        o4[1] = bf2f(pk.x >> 16)     + pbv + xv[1];
        o4[2] = bf2f(pk.y & 0xffffu) + pbv + xv[2];
        o4[3] = bf2f(pk.y >> 16)     + pbv + xv[3];
        *(f32x4*)(out + off) = o4;
    }
}

extern "C" void kernel_launch(void* const* d_in, const int* in_sizes, int n_in,
                              void* d_out, int out_size, void* d_ws, size_t ws_size,
                              hipStream_t stream) {
    const float* x     = (const float*)d_in[0];
    const float* gnw   = (const float*)d_in[1];
    const float* gnb   = (const float*)d_in[2];
    const float* qkvw  = (const float*)d_in[3];
    const float* projw = (const float*)d_in[4];
    const float* projb = (const float*)d_in[5];
    float* out = (float*)d_out;

    char* ws = (char*)d_ws;
    ushort* wbf   = (ushort*)(ws);                // 98,304 B
    float*  qsumP = (float*)(ws + 102400);        // 524,288 B
    ushort* mpp   = (ushort*)(ws + 626688);       // 524,288 B
    // sc/bi overlap mpp (disjoint lifetimes: k_stats writes, k_main reads,
    // THEN k_comb writes mpp; re-established identically every replay)
    float*  sc    = (float*)(ws + 626688);        // 8,192 B
    float*  bi    = (float*)(ws + 634880);        // 8,192 B
    float*  ctxP  = (float*)(ws + 1150976);       // 16,777,216 B
    ushort* eqT   = (ushort*)(ws + 17928192);     // 67,108,864 B (end: 85,037,056)

    k_pack <<<192,  256,  0, stream>>>(qkvw, wbf, 384 * 128);
    k_stats<<<512,  1024, 0, stream>>>(x, gnw, gnb, sc, bi);
    k_main <<<1024, 256,  0, stream>>>(x, wbf, sc, bi, eqT, qsumP, ctxP);
    k_red  <<<128,  256,  0, stream>>>(ctxP);
    k_comb <<<16,   256,  0, stream>>>(ctxP, qsumP, projw, mpp);
    k_final<<<2048, 256,  0, stream>>>(eqT, mpp, projb, x, out);
}

// Round 10
// 234.836 us; speedup vs baseline: 2.4802x; 1.0274x over previous
//
#include <hip/hip_runtime.h>

// R10: R9 with Phase-A packing bug fixed (i=3 corrupted wj.x via the i&1
// branch -> NaN). Packing now via explicit e[ch][n] array. All else = R9:
// 32-n chunks, LDS 28.7KB (xs 8KB + ksm/vls [4][32][40]), k_pack merged
// into k_stats, k_final = R8.

#define B_ 16
#define C_ 128
#define N_ 16384

typedef short bf16x8 __attribute__((ext_vector_type(8)));
typedef float f32x4 __attribute__((ext_vector_type(4)));
typedef unsigned u32x2 __attribute__((ext_vector_type(2)));

__device__ __forceinline__ ushort f2bf(float f) {
    union { float f; unsigned u; } v; v.f = f;
    unsigned r = (v.u + 0x7FFFu + ((v.u >> 16) & 1u)) >> 16;
    return (ushort)r;
}
__device__ __forceinline__ float bf2f(unsigned h) {
    union { unsigned u; float f; } v; v.u = h << 16;
    return v.f;
}

// ---------------- K1: GroupNorm stats -> sc/bi ; blocks >=512 pack qkv_w ----
__global__ void k_stats(const float* __restrict__ x, const float* __restrict__ gnw,
                        const float* __restrict__ gnb, float* __restrict__ sc,
                        float* __restrict__ bi,
                        const float* __restrict__ qkvw, ushort* __restrict__ wbf) {
    int bg = blockIdx.x;
    if (bg >= 512) {  // pack 49152 weights, 48 blocks x 1024
        int i = (bg - 512) * 1024 + threadIdx.x;
        if (i < 384 * 128) wbf[i] = f2bf(qkvw[i]);
        return;
    }
    const float4* p = (const float4*)(x + (size_t)bg * (4 * N_));
    float s = 0.f, s2 = 0.f;
    for (int i = threadIdx.x; i < N_; i += 1024) {
        float4 v = p[i];
        s  += v.x + v.y + v.z + v.w;
        s2 += v.x * v.x + v.y * v.y + v.z * v.z + v.w * v.w;
    }
    #pragma unroll
    for (int d = 32; d > 0; d >>= 1) { s += __shfl_xor(s, d); s2 += __shfl_xor(s2, d); }
    __shared__ float ls[16], ls2[16];
    int wid = threadIdx.x >> 6, lane = threadIdx.x & 63;
    if (lane == 0) { ls[wid] = s; ls2[wid] = s2; }
    __syncthreads();
    if (threadIdx.x == 0) {
        float S = 0.f, S2 = 0.f;
        #pragma unroll
        for (int i = 0; i < 16; ++i) { S += ls[i]; S2 += ls2[i]; }
        float m = S / 65536.f;
        float var = S2 / 65536.f - m * m;
        float rs = rsqrtf(var + 1e-5f);
        int b = bg >> 5, g = bg & 31;
        #pragma unroll
        for (int i = 0; i < 4; ++i) {
            int c = g * 4 + i;
            float scv = rs * gnw[c];
            sc[b * 128 + c] = scv;
            bi[b * 128 + c] = gnb[c] - m * scv;
        }
    }
}

// ---------------- K2: fused normalize+transpose+qkv+exp(q)+ksm+v+MFMA-ctx ----------
// wave0: q0..q5 | wave1: q6,q7,k(h0),k(h1) | wave2: k(h2),k(h3),v16,v17 | wave3: v18..23

#define MFMA16(A, Bv, Cc) __builtin_amdgcn_mfma_f32_16x16x32_bf16(A, Bv, Cc, 0, 0, 0)

#define DO_Q(J, OT) do { \
    f32x4 acc = {0.f, 0.f, 0.f, 0.f}; \
    acc = MFMA16(wf[J][0], xb[0], acc); acc = MFMA16(wf[J][1], xb[1], acc); \
    acc = MFMA16(wf[J][2], xb[2], acc); acc = MFMA16(wf[J][3], xb[3], acc); \
    float e0 = __expf(acc[0]), e1 = __expf(acc[1]); \
    float e2 = __expf(acc[2]), e3 = __expf(acc[3]); \
    qacc[J][0] += e0; qacc[J][1] += e1; qacc[J][2] += e2; qacc[J][3] += e3; \
    u32x2 pkq; \
    pkq.x = (unsigned)f2bf(e0) | ((unsigned)f2bf(e1) << 16); \
    pkq.y = (unsigned)f2bf(e2) | ((unsigned)f2bf(e3) << 16); \
    *(u32x2*)(eqp + (OT) * 16) = pkq; \
} while (0)

#define DO_K(JLO, H) do { \
    f32x4 aL = {0.f, 0.f, 0.f, 0.f}, aH = {0.f, 0.f, 0.f, 0.f}; \
    aL = MFMA16(wf[JLO][0], xb[0], aL);     aH = MFMA16(wf[(JLO)+1][0], xb[0], aH); \
    aL = MFMA16(wf[JLO][1], xb[1], aL);     aH = MFMA16(wf[(JLO)+1][1], xb[1], aH); \
    aL = MFMA16(wf[JLO][2], xb[2], aL);     aH = MFMA16(wf[(JLO)+1][2], xb[2], aH); \
    aL = MFMA16(wf[JLO][3], xb[3], aL);     aH = MFMA16(wf[(JLO)+1][3], xb[3], aH); \
    float eL0 = __expf(aL[0]), eL1 = __expf(aL[1]), eL2 = __expf(aL[2]), eL3 = __expf(aL[3]); \
    float eH0 = __expf(aH[0]), eH1 = __expf(aH[1]), eH2 = __expf(aH[2]), eH3 = __expf(aH[3]); \
    float s = eL0 + eL1 + eL2 + eL3 + eH0 + eH1 + eH2 + eH3; \
    s += __shfl_xor(s, 16); s += __shfl_xor(s, 32); \
    float rinv = 1.f / s; \
    ksm[H][lg * 4 + 0][nloc] = f2bf(eL0 * rinv); \
    ksm[H][lg * 4 + 1][nloc] = f2bf(eL1 * rinv); \
    ksm[H][lg * 4 + 2][nloc] = f2bf(eL2 * rinv); \
    ksm[H][lg * 4 + 3][nloc] = f2bf(eL3 * rinv); \
    ksm[H][16 + lg * 4 + 0][nloc] = f2bf(eH0 * rinv); \
    ksm[H][16 + lg * 4 + 1][nloc] = f2bf(eH1 * rinv); \
    ksm[H][16 + lg * 4 + 2][nloc] = f2bf(eH2 * rinv); \
    ksm[H][16 + lg * 4 + 3][nloc] = f2bf(eH3 * rinv); \
} while (0)

#define DO_V(J, HV, EB) do { \
    f32x4 acc = {0.f, 0.f, 0.f, 0.f}; \
    acc = MFMA16(wf[J][0], xb[0], acc); acc = MFMA16(wf[J][1], xb[1], acc); \
    acc = MFMA16(wf[J][2], xb[2], acc); acc = MFMA16(wf[J][3], xb[3], acc); \
    vls[HV][(EB) + lg * 4 + 0][nloc] = f2bf(acc[0]); \
    vls[HV][(EB) + lg * 4 + 1][nloc] = f2bf(acc[1]); \
    vls[HV][(EB) + lg * 4 + 2][nloc] = f2bf(acc[2]); \
    vls[HV][(EB) + lg * 4 + 3][nloc] = f2bf(acc[3]); \
} while (0)

__global__ __launch_bounds__(256, 2) void k_main(
    const float* __restrict__ x, const ushort* __restrict__ wbf,
    const float* __restrict__ scA, const float* __restrict__ biA,
    ushort* __restrict__ eqT, float* __restrict__ qsumP, float* __restrict__ ctxP) {
    int blk = blockIdx.x;
    int b = blk >> 6, nb = blk & 63;
    int tid = threadIdx.x, wid = tid >> 6, lane = tid & 63;
    int l15 = lane & 15, lg = lane >> 4;

    // xs: 32 n-rows x 128 c bf16, row = 256 B, 16B-slot XOR-swizzled by (n&7)
    __shared__ __align__(16) ushort xs[4096];        // 8 KB
    __shared__ __align__(16) ushort ksm[4][32][40];  // 10,240 B
    __shared__ __align__(16) ushort vls[4][32][40];  // 10,240 B

    // weight fragments, register-resident for the whole kernel
    bf16x8 wf[6][4];
    {
        const ushort* wr = wbf + (size_t)(wid * 96 + l15) * 128 + lg * 8;
        #pragma unroll
        for (int j = 0; j < 6; ++j)
            #pragma unroll
            for (int kc = 0; kc < 4; ++kc)
                wf[j][kc] = *(const bf16x8*)(wr + j * 2048 + kc * 32);
    }

    float qacc[6][4];
    #pragma unroll
    for (int j = 0; j < 6; ++j)
        #pragma unroll
        for (int r = 0; r < 4; ++r) qacc[j][r] = 0.f;
    f32x4 cacc[2][2];
    #pragma unroll
    for (int di = 0; di < 2; ++di)
        #pragma unroll
        for (int ei = 0; ei < 2; ++ei) cacc[di][ei] = (f32x4){0.f, 0.f, 0.f, 0.f};

    // Phase-A constants: thread (pk_ 0..7, pcb 0..31): loads float4 (4 n) of
    // channels c = pcb*4..+3, register-transposes, 4x b64 writes into xs.
    const int pk_ = tid & 7, pcb = tid >> 3;
    const float* xrow = x + (size_t)b * (C_ * N_) + nb * 256 + pk_ * 4;
    float scv[4], biv[4];
    #pragma unroll
    for (int i = 0; i < 4; ++i) {
        scv[i] = scA[b * 128 + pcb * 4 + i];
        biv[i] = biA[b * 128 + pcb * 4 + i];
    }
    unsigned boffj[4];
    #pragma unroll
    for (int j = 0; j < 4; ++j) {
        int n = pk_ * 4 + j;
        boffj[j] = (unsigned)(n * 256 + (((pcb >> 1) * 16) ^ ((n & 7) << 4)) + (pcb & 1) * 8);
    }

    for (int ch = 0; ch < 8; ++ch) {
        __syncthreads();  // prev chunk's xs/ksm/vls reads complete
        // ---- Phase A: x -> normalized bf16 -> xs (swizzled [n][c])
        unsigned e[4][4];  // [channel i][n j]
        #pragma unroll
        for (int i = 0; i < 4; ++i) {
            float4 v = *(const float4*)(xrow + (size_t)(pcb * 4 + i) * N_ + ch * 32);
            float s = scv[i], t = biv[i];
            e[i][0] = f2bf(v.x * s + t);
            e[i][1] = f2bf(v.y * s + t);
            e[i][2] = f2bf(v.z * s + t);
            e[i][3] = f2bf(v.w * s + t);
        }
        #pragma unroll
        for (int j = 0; j < 4; ++j) {
            u32x2 wj;
            wj.x = e[0][j] | (e[1][j] << 16);
            wj.y = e[2][j] | (e[3][j] << 16);
            *(u32x2*)((char*)xs + boffj[j]) = wj;
        }
        __syncthreads();

        // ---- Phase B: per 16-n tile (nt 0,1): xb via swizzled b128 reads
        #pragma unroll
        for (int nt = 0; nt < 2; ++nt) {
            int row = nt * 16 + l15;
            bf16x8 xb[4];
            #pragma unroll
            for (int kc = 0; kc < 4; ++kc) {
                unsigned off = (unsigned)(row * 256 +
                    (((kc * 4 + lg) * 16) ^ ((row & 7) << 4)));
                xb[kc] = *(const bf16x8*)((const char*)xs + off);
            }
            int nloc = nt * 16 + l15;
            int ng = nb * 256 + ch * 32 + nloc;
            ushort* eqp = eqT + ((size_t)b * N_ + ng) * 128 + lg * 4;

            if (wid == 0) {
                DO_Q(0, 0); DO_Q(1, 1); DO_Q(2, 2); DO_Q(3, 3); DO_Q(4, 4); DO_Q(5, 5);
            } else if (wid == 1) {
                DO_Q(0, 6); DO_Q(1, 7); DO_K(2, 0); DO_K(4, 1);
            } else if (wid == 2) {
                DO_K(0, 2); DO_K(2, 3); DO_V(4, 0, 0); DO_V(5, 0, 16);
            } else {
                DO_V(0, 1, 0); DO_V(1, 1, 16); DO_V(2, 2, 0);
                DO_V(3, 2, 16); DO_V(4, 3, 0); DO_V(5, 3, 16);
            }
        }
        __syncthreads();

        // ---- Phase C: ctx[d][e] += ksm . vls^T over this chunk's 32 n (K=32)
        {
            bf16x8 A0 = *(const bf16x8*)&ksm[wid][l15][lg * 8];
            bf16x8 A1 = *(const bf16x8*)&ksm[wid][16 + l15][lg * 8];
            bf16x8 B0 = *(const bf16x8*)&vls[wid][l15][lg * 8];
            bf16x8 B1 = *(const bf16x8*)&vls[wid][16 + l15][lg * 8];
            cacc[0][0] = MFMA16(A0, B0, cacc[0][0]);
            cacc[0][1] = MFMA16(A0, B1, cacc[0][1]);
            cacc[1][0] = MFMA16(A1, B0, cacc[1][0]);
            cacc[1][1] = MFMA16(A1, B1, cacc[1][1]);
        }
    }

    // ---- qsum: reduce register accumulators over the 16 n-columns (l15 lanes)
    int nq = (wid == 0) ? 6 : (wid == 1 ? 2 : 0);
    #pragma unroll
    for (int j = 0; j < 6; ++j) {
        if (j < nq) {
            #pragma unroll
            for (int r = 0; r < 4; ++r) {
                float s = qacc[j][r];
                s += __shfl_xor(s, 1); s += __shfl_xor(s, 2);
                s += __shfl_xor(s, 4); s += __shfl_xor(s, 8);
                if (l15 == 0)
                    qsumP[(size_t)blk * 128 + (wid * 6 + j) * 16 + lg * 4 + r] = s;
            }
        }
    }
    // ---- ctx partials out (head = wid): D layout col=l15(e), row=lg*4+r(d)
    float* cp = ctxP + (size_t)blk * 4096 + wid * 1024;
    #pragma unroll
    for (int di = 0; di < 2; ++di)
        #pragma unroll
        for (int ei = 0; ei < 2; ++ei)
            #pragma unroll
            for (int r = 0; r < 4; ++r)
                cp[(di * 16 + lg * 4 + r) * 32 + ei * 16 + l15] = cacc[di][ei][r];
}

// ---------------- K2.5: reduce ctxP over the 64 n-blocks (into q=0 slice) ----
__global__ void k_red(float* __restrict__ ctxP) {
    int blk = blockIdx.x;  // B*8
    int b = blk >> 3, sl = blk & 7;
    float* base = ctxP + (size_t)b * 64 * 4096;
    #pragma unroll
    for (int r = 0; r < 2; ++r) {
        int i = sl * 512 + r * 256 + threadIdx.x;
        float s = 0.f;
        for (int q = 0; q < 64; ++q) s += base[(size_t)q * 4096 + i];
        base[i] = s;
    }
}

// ---------------- K3: combine partials, build M''[b][c][hd] bf16 ----------------
__global__ void k_comb(const float* __restrict__ ctxP, const float* __restrict__ qsumP,
                       const float* __restrict__ projw, ushort* __restrict__ mpp) {
    int b = blockIdx.x, tid = threadIdx.x;
    __shared__ float ctx[4096];
    __shared__ float qinv[128];
    for (int i = tid; i < 4096; i += 256)
        ctx[i] = ctxP[(size_t)b * 64 * 4096 + i];
    if (tid < 128) {
        float s = 0.f;
        const float* p = qsumP + (size_t)b * 64 * 128 + tid;
        for (int q = 0; q < 64; ++q) s += p[q * 128];
        qinv[tid] = 1.f / s;
    }
    __syncthreads();
    int c = tid >> 1, hd0 = (tid & 1) * 64;
    unsigned ow[32];
    for (int k = 0; k < 64; ++k) {
        int hd = hd0 + k, h = hd >> 5, d = hd & 31;
        const float* pw = projw + c * 128 + h * 32;
        const float* cx = ctx + h * 1024 + d * 32;
        float s = 0.f;
        #pragma unroll 8
        for (int e = 0; e < 32; ++e) s += pw[e] * cx[e];
        s *= qinv[hd];
        ushort bv = f2bf(s);
        if (k & 1) ow[k >> 1] |= ((unsigned)bv) << 16; else ow[k >> 1] = bv;
    }
    ushort* dst = mpp + ((size_t)(b * 128 + c)) * 128 + hd0;
    #pragma unroll
    for (int q = 0; q < 8; ++q) {
        uint4 t; t.x = ow[q * 4]; t.y = ow[q * 4 + 1]; t.z = ow[q * 4 + 2]; t.w = ow[q * 4 + 3];
        ((uint4*)dst)[q] = t;
    }
}

// ---------------- K4: out = expq . M''^T + proj_b + x (R8 structure) ----------------
__global__ __launch_bounds__(256) void k_final(
    const ushort* __restrict__ eqT, const ushort* __restrict__ mpp,
    const float* __restrict__ projb, const float* __restrict__ x,
    float* __restrict__ out) {
    int blk = blockIdx.x;
    int b = blk >> 7, nb = blk & 127;
    int tid = threadIdx.x, wid = tid >> 6, lane = tid & 63;
    int l15 = lane & 15, lg = lane >> 4;

    __shared__ __align__(16) ushort att[16384];  // 32 KB: [c 128][n 128] bf16 swizzled

    bf16x8 bm[2][4];
    #pragma unroll
    for (int ctk = 0; ctk < 2; ++ctk) {
        const ushort* br = mpp + ((size_t)(b * 128 + (wid * 2 + ctk) * 16 + l15)) * 128 + lg * 8;
        #pragma unroll
        for (int kc = 0; kc < 4; ++kc) bm[ctk][kc] = *(const bf16x8*)(br + kc * 32);
    }

    int n0 = nb * 128;
    #pragma unroll
    for (int nt = 0; nt < 8; ++nt) {
        const ushort* ar = eqT + ((size_t)b * N_ + n0 + nt * 16 + l15) * 128 + lg * 8;
        bf16x8 af[4];
        #pragma unroll
        for (int kc = 0; kc < 4; ++kc) af[kc] = *(const bf16x8*)(ar + kc * 32);
        #pragma unroll
        for (int ctk = 0; ctk < 2; ++ctk) {
            f32x4 a = {0.f, 0.f, 0.f, 0.f};
            #pragma unroll
            for (int kc = 0; kc < 4; ++kc) a = MFMA16(af[kc], bm[ctk][kc], a);
            int c = (wid * 2 + ctk) * 16 + l15;
            int nloc = nt * 16 + lg * 4;
            unsigned byte = (unsigned)(c * 256 + ((nloc * 2) ^ ((c & 15) << 4)));
            u32x2 pk;
            pk.x = (unsigned)f2bf(a[0]) | ((unsigned)f2bf(a[1]) << 16);
            pk.y = (unsigned)f2bf(a[2]) | ((unsigned)f2bf(a[3]) << 16);
            *(u32x2*)((char*)att + byte) = pk;
        }
    }
    __syncthreads();

    int crow = lane >> 5;
    int n4 = (lane & 31) * 4;
    #pragma unroll
    for (int it = 0; it < 16; ++it) {
        int c = wid * 32 + it * 2 + crow;
        unsigned byte = (unsigned)(c * 256 + ((n4 * 2) ^ ((c & 15) << 4)));
        u32x2 pk = *(const u32x2*)((const char*)att + byte);
        size_t off = (size_t)(b * C_ + c) * N_ + n0 + n4;
        f32x4 xv = __builtin_nontemporal_load((const f32x4*)(x + off));
        float pbv = projb[c];
        f32x4 o4;
        o4[0] = bf2f(pk.x & 0xffffu) + pbv + xv[0];
        o4[1] = bf2f(pk.x >> 16)     + pbv + xv[1];
        o4[2] = bf2f(pk.y & 0xffffu) + pbv + xv[2];
        o4[3] = bf2f(pk.y >> 16)     + pbv + xv[3];
        *(f32x4*)(out + off) = o4;
    }
}

extern "C" void kernel_launch(void* const* d_in, const int* in_sizes, int n_in,
                              void* d_out, int out_size, void* d_ws, size_t ws_size,
                              hipStream_t stream) {
    const float* x     = (const float*)d_in[0];
    const float* gnw   = (const float*)d_in[1];
    const float* gnb   = (const float*)d_in[2];
    const float* qkvw  = (const float*)d_in[3];
    const float* projw = (const float*)d_in[4];
    const float* projb = (const float*)d_in[5];
    float* out = (float*)d_out;

    char* ws = (char*)d_ws;
    ushort* wbf   = (ushort*)(ws);                // 98,304 B
    float*  qsumP = (float*)(ws + 102400);        // 524,288 B
    ushort* mpp   = (ushort*)(ws + 626688);       // 524,288 B
    // sc/bi overlap mpp (disjoint lifetimes: k_stats writes, k_main reads,
    // THEN k_comb writes mpp; re-established identically every replay)
    float*  sc    = (float*)(ws + 626688);        // 8,192 B
    float*  bi    = (float*)(ws + 634880);        // 8,192 B
    float*  ctxP  = (float*)(ws + 1150976);       // 16,777,216 B
    ushort* eqT   = (ushort*)(ws + 17928192);     // 67,108,864 B (end: 85,037,056)

    k_stats<<<560,  1024, 0, stream>>>(x, gnw, gnb, sc, bi, qkvw, wbf);
    k_main <<<1024, 256,  0, stream>>>(x, wbf, sc, bi, eqT, qsumP, ctxP);
    k_red  <<<128,  256,  0, stream>>>(ctxP);
    k_comb <<<16,   256,  0, stream>>>(ctxP, qsumP, projw, mpp);
    k_final<<<2048, 256,  0, stream>>>(eqT, mpp, projb, x, out);
}

// Round 11
// 215.442 us; speedup vs baseline: 2.7035x; 1.0900x over previous
//
#include <hip/hip_runtime.h>

// R11: eqT eliminated (-134 MB round-trip). k_main no longer stores exp(q)
// (only qsum partials + ctx partials); k_final recomputes eq = exp(Wq.xn)
// from x (which it reads anyway for the residual), bitwise-identical math.
// k_final v4: 64n x 128c blocks, grid 4096; xs -> q-MFMA -> eqls -> out-MFMA
// -> att (aliases xs) -> coalesced store. sc/bi moved to dedicated ws slots
// (now consumed after k_comb writes mpp).

#define B_ 16
#define C_ 128
#define N_ 16384

typedef short bf16x8 __attribute__((ext_vector_type(8)));
typedef float f32x4 __attribute__((ext_vector_type(4)));
typedef unsigned u32x2 __attribute__((ext_vector_type(2)));

__device__ __forceinline__ ushort f2bf(float f) {
    union { float f; unsigned u; } v; v.f = f;
    unsigned r = (v.u + 0x7FFFu + ((v.u >> 16) & 1u)) >> 16;
    return (ushort)r;
}
__device__ __forceinline__ float bf2f(unsigned h) {
    union { unsigned u; float f; } v; v.u = h << 16;
    return v.f;
}

// ---------------- K1: GroupNorm stats -> sc/bi ; blocks >=512 pack qkv_w ----
__global__ void k_stats(const float* __restrict__ x, const float* __restrict__ gnw,
                        const float* __restrict__ gnb, float* __restrict__ sc,
                        float* __restrict__ bi,
                        const float* __restrict__ qkvw, ushort* __restrict__ wbf) {
    int bg = blockIdx.x;
    if (bg >= 512) {  // pack 49152 weights, 48 blocks x 1024
        int i = (bg - 512) * 1024 + threadIdx.x;
        if (i < 384 * 128) wbf[i] = f2bf(qkvw[i]);
        return;
    }
    const float4* p = (const float4*)(x + (size_t)bg * (4 * N_));
    float s = 0.f, s2 = 0.f;
    for (int i = threadIdx.x; i < N_; i += 1024) {
        float4 v = p[i];
        s  += v.x + v.y + v.z + v.w;
        s2 += v.x * v.x + v.y * v.y + v.z * v.z + v.w * v.w;
    }
    #pragma unroll
    for (int d = 32; d > 0; d >>= 1) { s += __shfl_xor(s, d); s2 += __shfl_xor(s2, d); }
    __shared__ float ls[16], ls2[16];
    int wid = threadIdx.x >> 6, lane = threadIdx.x & 63;
    if (lane == 0) { ls[wid] = s; ls2[wid] = s2; }
    __syncthreads();
    if (threadIdx.x == 0) {
        float S = 0.f, S2 = 0.f;
        #pragma unroll
        for (int i = 0; i < 16; ++i) { S += ls[i]; S2 += ls2[i]; }
        float m = S / 65536.f;
        float var = S2 / 65536.f - m * m;
        float rs = rsqrtf(var + 1e-5f);
        int b = bg >> 5, g = bg & 31;
        #pragma unroll
        for (int i = 0; i < 4; ++i) {
            int c = g * 4 + i;
            float scv = rs * gnw[c];
            sc[b * 128 + c] = scv;
            bi[b * 128 + c] = gnb[c] - m * scv;
        }
    }
}

// ---------------- K2: normalize+transpose+qkv+qsum+ksm+v+MFMA-ctx (no eqT) --------
// wave0: q0..q5 | wave1: q6,q7,k(h0),k(h1) | wave2: k(h2),k(h3),v16,v17 | wave3: v18..23

#define MFMA16(A, Bv, Cc) __builtin_amdgcn_mfma_f32_16x16x32_bf16(A, Bv, Cc, 0, 0, 0)

#define DO_Q(J) do { \
    f32x4 acc = {0.f, 0.f, 0.f, 0.f}; \
    acc = MFMA16(wf[J][0], xb[0], acc); acc = MFMA16(wf[J][1], xb[1], acc); \
    acc = MFMA16(wf[J][2], xb[2], acc); acc = MFMA16(wf[J][3], xb[3], acc); \
    qacc[J][0] += __expf(acc[0]); qacc[J][1] += __expf(acc[1]); \
    qacc[J][2] += __expf(acc[2]); qacc[J][3] += __expf(acc[3]); \
} while (0)

#define DO_K(JLO, H) do { \
    f32x4 aL = {0.f, 0.f, 0.f, 0.f}, aH = {0.f, 0.f, 0.f, 0.f}; \
    aL = MFMA16(wf[JLO][0], xb[0], aL);     aH = MFMA16(wf[(JLO)+1][0], xb[0], aH); \
    aL = MFMA16(wf[JLO][1], xb[1], aL);     aH = MFMA16(wf[(JLO)+1][1], xb[1], aH); \
    aL = MFMA16(wf[JLO][2], xb[2], aL);     aH = MFMA16(wf[(JLO)+1][2], xb[2], aH); \
    aL = MFMA16(wf[JLO][3], xb[3], aL);     aH = MFMA16(wf[(JLO)+1][3], xb[3], aH); \
    float eL0 = __expf(aL[0]), eL1 = __expf(aL[1]), eL2 = __expf(aL[2]), eL3 = __expf(aL[3]); \
    float eH0 = __expf(aH[0]), eH1 = __expf(aH[1]), eH2 = __expf(aH[2]), eH3 = __expf(aH[3]); \
    float s = eL0 + eL1 + eL2 + eL3 + eH0 + eH1 + eH2 + eH3; \
    s += __shfl_xor(s, 16); s += __shfl_xor(s, 32); \
    float rinv = 1.f / s; \
    ksm[H][lg * 4 + 0][nloc] = f2bf(eL0 * rinv); \
    ksm[H][lg * 4 + 1][nloc] = f2bf(eL1 * rinv); \
    ksm[H][lg * 4 + 2][nloc] = f2bf(eL2 * rinv); \
    ksm[H][lg * 4 + 3][nloc] = f2bf(eL3 * rinv); \
    ksm[H][16 + lg * 4 + 0][nloc] = f2bf(eH0 * rinv); \
    ksm[H][16 + lg * 4 + 1][nloc] = f2bf(eH1 * rinv); \
    ksm[H][16 + lg * 4 + 2][nloc] = f2bf(eH2 * rinv); \
    ksm[H][16 + lg * 4 + 3][nloc] = f2bf(eH3 * rinv); \
} while (0)

#define DO_V(J, HV, EB) do { \
    f32x4 acc = {0.f, 0.f, 0.f, 0.f}; \
    acc = MFMA16(wf[J][0], xb[0], acc); acc = MFMA16(wf[J][1], xb[1], acc); \
    acc = MFMA16(wf[J][2], xb[2], acc); acc = MFMA16(wf[J][3], xb[3], acc); \
    vls[HV][(EB) + lg * 4 + 0][nloc] = f2bf(acc[0]); \
    vls[HV][(EB) + lg * 4 + 1][nloc] = f2bf(acc[1]); \
    vls[HV][(EB) + lg * 4 + 2][nloc] = f2bf(acc[2]); \
    vls[HV][(EB) + lg * 4 + 3][nloc] = f2bf(acc[3]); \
} while (0)

__global__ __launch_bounds__(256, 2) void k_main(
    const float* __restrict__ x, const ushort* __restrict__ wbf,
    const float* __restrict__ scA, const float* __restrict__ biA,
    float* __restrict__ qsumP, float* __restrict__ ctxP) {
    int blk = blockIdx.x;
    int b = blk >> 6, nb = blk & 63;
    int tid = threadIdx.x, wid = tid >> 6, lane = tid & 63;
    int l15 = lane & 15, lg = lane >> 4;

    __shared__ __align__(16) ushort xs[4096];        // 8 KB, [32 n][128 c] swizzled
    __shared__ __align__(16) ushort ksm[4][32][40];  // 10,240 B
    __shared__ __align__(16) ushort vls[4][32][40];  // 10,240 B

    bf16x8 wf[6][4];
    {
        const ushort* wr = wbf + (size_t)(wid * 96 + l15) * 128 + lg * 8;
        #pragma unroll
        for (int j = 0; j < 6; ++j)
            #pragma unroll
            for (int kc = 0; kc < 4; ++kc)
                wf[j][kc] = *(const bf16x8*)(wr + j * 2048 + kc * 32);
    }

    float qacc[6][4];
    #pragma unroll
    for (int j = 0; j < 6; ++j)
        #pragma unroll
        for (int r = 0; r < 4; ++r) qacc[j][r] = 0.f;
    f32x4 cacc[2][2];
    #pragma unroll
    for (int di = 0; di < 2; ++di)
        #pragma unroll
        for (int ei = 0; ei < 2; ++ei) cacc[di][ei] = (f32x4){0.f, 0.f, 0.f, 0.f};

    const int pk_ = tid & 7, pcb = tid >> 3;
    const float* xrow = x + (size_t)b * (C_ * N_) + nb * 256 + pk_ * 4;
    float scv[4], biv[4];
    #pragma unroll
    for (int i = 0; i < 4; ++i) {
        scv[i] = scA[b * 128 + pcb * 4 + i];
        biv[i] = biA[b * 128 + pcb * 4 + i];
    }
    unsigned boffj[4];
    #pragma unroll
    for (int j = 0; j < 4; ++j) {
        int n = pk_ * 4 + j;
        boffj[j] = (unsigned)(n * 256 + (((pcb >> 1) * 16) ^ ((n & 7) << 4)) + (pcb & 1) * 8);
    }

    for (int ch = 0; ch < 8; ++ch) {
        __syncthreads();
        unsigned e[4][4];
        #pragma unroll
        for (int i = 0; i < 4; ++i) {
            float4 v = *(const float4*)(xrow + (size_t)(pcb * 4 + i) * N_ + ch * 32);
            float s = scv[i], t = biv[i];
            e[i][0] = f2bf(v.x * s + t);
            e[i][1] = f2bf(v.y * s + t);
            e[i][2] = f2bf(v.z * s + t);
            e[i][3] = f2bf(v.w * s + t);
        }
        #pragma unroll
        for (int j = 0; j < 4; ++j) {
            u32x2 wj;
            wj.x = e[0][j] | (e[1][j] << 16);
            wj.y = e[2][j] | (e[3][j] << 16);
            *(u32x2*)((char*)xs + boffj[j]) = wj;
        }
        __syncthreads();

        #pragma unroll
        for (int nt = 0; nt < 2; ++nt) {
            int row = nt * 16 + l15;
            bf16x8 xb[4];
            #pragma unroll
            for (int kc = 0; kc < 4; ++kc) {
                unsigned off = (unsigned)(row * 256 +
                    (((kc * 4 + lg) * 16) ^ ((row & 7) << 4)));
                xb[kc] = *(const bf16x8*)((const char*)xs + off);
            }
            int nloc = nt * 16 + l15;

            if (wid == 0) {
                DO_Q(0); DO_Q(1); DO_Q(2); DO_Q(3); DO_Q(4); DO_Q(5);
            } else if (wid == 1) {
                DO_Q(0); DO_Q(1); DO_K(2, 0); DO_K(4, 1);
            } else if (wid == 2) {
                DO_K(0, 2); DO_K(2, 3); DO_V(4, 0, 0); DO_V(5, 0, 16);
            } else {
                DO_V(0, 1, 0); DO_V(1, 1, 16); DO_V(2, 2, 0);
                DO_V(3, 2, 16); DO_V(4, 3, 0); DO_V(5, 3, 16);
            }
        }
        __syncthreads();

        {
            bf16x8 A0 = *(const bf16x8*)&ksm[wid][l15][lg * 8];
            bf16x8 A1 = *(const bf16x8*)&ksm[wid][16 + l15][lg * 8];
            bf16x8 B0 = *(const bf16x8*)&vls[wid][l15][lg * 8];
            bf16x8 B1 = *(const bf16x8*)&vls[wid][16 + l15][lg * 8];
            cacc[0][0] = MFMA16(A0, B0, cacc[0][0]);
            cacc[0][1] = MFMA16(A0, B1, cacc[0][1]);
            cacc[1][0] = MFMA16(A1, B0, cacc[1][0]);
            cacc[1][1] = MFMA16(A1, B1, cacc[1][1]);
        }
    }

    int nq = (wid == 0) ? 6 : (wid == 1 ? 2 : 0);
    #pragma unroll
    for (int j = 0; j < 6; ++j) {
        if (j < nq) {
            #pragma unroll
            for (int r = 0; r < 4; ++r) {
                float s = qacc[j][r];
                s += __shfl_xor(s, 1); s += __shfl_xor(s, 2);
                s += __shfl_xor(s, 4); s += __shfl_xor(s, 8);
                if (l15 == 0)
                    qsumP[(size_t)blk * 128 + (wid * 6 + j) * 16 + lg * 4 + r] = s;
            }
        }
    }
    float* cp = ctxP + (size_t)blk * 4096 + wid * 1024;
    #pragma unroll
    for (int di = 0; di < 2; ++di)
        #pragma unroll
        for (int ei = 0; ei < 2; ++ei)
            #pragma unroll
            for (int r = 0; r < 4; ++r)
                cp[(di * 16 + lg * 4 + r) * 32 + ei * 16 + l15] = cacc[di][ei][r];
}

// ---------------- K2.5: reduce ctxP over the 64 n-blocks (into q=0 slice) ----
__global__ void k_red(float* __restrict__ ctxP) {
    int blk = blockIdx.x;  // B*8
    int b = blk >> 3, sl = blk & 7;
    float* base = ctxP + (size_t)b * 64 * 4096;
    #pragma unroll
    for (int r = 0; r < 2; ++r) {
        int i = sl * 512 + r * 256 + threadIdx.x;
        float s = 0.f;
        for (int q = 0; q < 64; ++q) s += base[(size_t)q * 4096 + i];
        base[i] = s;
    }
}

// ---------------- K3: combine partials, build M''[b][c][hd] bf16 ----------------
__global__ void k_comb(const float* __restrict__ ctxP, const float* __restrict__ qsumP,
                       const float* __restrict__ projw, ushort* __restrict__ mpp) {
    int b = blockIdx.x, tid = threadIdx.x;
    __shared__ float ctx[4096];
    __shared__ float qinv[128];
    for (int i = tid; i < 4096; i += 256)
        ctx[i] = ctxP[(size_t)b * 64 * 4096 + i];
    if (tid < 128) {
        float s = 0.f;
        const float* p = qsumP + (size_t)b * 64 * 128 + tid;
        for (int q = 0; q < 64; ++q) s += p[q * 128];
        qinv[tid] = 1.f / s;
    }
    __syncthreads();
    int c = tid >> 1, hd0 = (tid & 1) * 64;
    unsigned ow[32];
    for (int k = 0; k < 64; ++k) {
        int hd = hd0 + k, h = hd >> 5, d = hd & 31;
        const float* pw = projw + c * 128 + h * 32;
        const float* cx = ctx + h * 1024 + d * 32;
        float s = 0.f;
        #pragma unroll 8
        for (int e = 0; e < 32; ++e) s += pw[e] * cx[e];
        s *= qinv[hd];
        ushort bv = f2bf(s);
        if (k & 1) ow[k >> 1] |= ((unsigned)bv) << 16; else ow[k >> 1] = bv;
    }
    ushort* dst = mpp + ((size_t)(b * 128 + c)) * 128 + hd0;
    #pragma unroll
    for (int q = 0; q < 8; ++q) {
        uint4 t; t.x = ow[q * 4]; t.y = ow[q * 4 + 1]; t.z = ow[q * 4 + 2]; t.w = ow[q * 4 + 3];
        ((uint4*)dst)[q] = t;
    }
}

// ---------------- K4: recompute eq, out = eq . M''^T + proj_b + x ----------------
// Block = 64 n x 128 c, grid 4096. Phases:
//  A: x -> normalized bf16 -> xs[64n][128c] (swizzled)
//  B: q-MFMA (wave: 2 o-tiles) -> exp -> eqls[64n][128hd] (swizzled)
//  C: out-MFMA (A=eqls frag, B=mpp frag) -> att[128c][64n] (aliases xs)
//  D: coalesced readback + residual + store
__global__ __launch_bounds__(256) void k_final(
    const ushort* __restrict__ wbf, const ushort* __restrict__ mpp,
    const float* __restrict__ scA, const float* __restrict__ biA,
    const float* __restrict__ projb, const float* __restrict__ x,
    float* __restrict__ out) {
    int blk = blockIdx.x;
    int b = blk >> 8, nb = blk & 255;
    int tid = threadIdx.x, wid = tid >> 6, lane = tid & 63;
    int l15 = lane & 15, lg = lane >> 4;
    int n0 = nb * 64;

    __shared__ __align__(16) char lds[32768];
    ushort* xs   = (ushort*)lds;            // 16 KB, dead after Phase B
    ushort* att  = (ushort*)lds;            // 16 KB, aliases xs (barrier-separated)
    ushort* eqls = (ushort*)(lds + 16384);  // 16 KB

    // q-weight fragments (o rows 0..127): wave owns ot = wid*2, wid*2+1
    bf16x8 wq[2][4];
    #pragma unroll
    for (int j = 0; j < 2; ++j) {
        const ushort* wr = wbf + (size_t)((wid * 2 + j) * 16 + l15) * 128 + lg * 8;
        #pragma unroll
        for (int kc = 0; kc < 4; ++kc) wq[j][kc] = *(const bf16x8*)(wr + kc * 32);
    }
    // mpp fragments: wave owns ct = wid*2, wid*2+1
    bf16x8 bm[2][4];
    #pragma unroll
    for (int ctk = 0; ctk < 2; ++ctk) {
        const ushort* br = mpp + ((size_t)(b * 128 + (wid * 2 + ctk) * 16 + l15)) * 128 + lg * 8;
        #pragma unroll
        for (int kc = 0; kc < 4; ++kc) bm[ctk][kc] = *(const bf16x8*)(br + kc * 32);
    }

    // ---- Phase A: x -> xs (R5 mapping: pk_=tid&15 -> 4n, pcb=tid>>4 -> 8c)
    {
        const int pk_ = tid & 15, pcb = tid >> 4;
        const float* xrow = x + (size_t)b * (C_ * N_) + n0 + pk_ * 4;
        unsigned e[8][4];
        #pragma unroll
        for (int i = 0; i < 8; ++i) {
            int c = pcb * 8 + i;
            float s = scA[b * 128 + c], t = biA[b * 128 + c];
            float4 v = *(const float4*)(xrow + (size_t)c * N_);
            e[i][0] = f2bf(v.x * s + t);
            e[i][1] = f2bf(v.y * s + t);
            e[i][2] = f2bf(v.z * s + t);
            e[i][3] = f2bf(v.w * s + t);
        }
        #pragma unroll
        for (int j = 0; j < 4; ++j) {
            int n = pk_ * 4 + j;
            uint4 wj;
            wj.x = e[0][j] | (e[1][j] << 16);
            wj.y = e[2][j] | (e[3][j] << 16);
            wj.z = e[4][j] | (e[5][j] << 16);
            wj.w = e[6][j] | (e[7][j] << 16);
            unsigned byte = (unsigned)(n * 256 + ((pcb * 16) ^ ((n & 7) << 4)));
            *(uint4*)((char*)xs + byte) = wj;
        }
    }
    __syncthreads();

    // ---- Phase B: q-MFMA + exp -> eqls[n][hd]
    #pragma unroll
    for (int nt = 0; nt < 4; ++nt) {
        int row = nt * 16 + l15;
        bf16x8 xb[4];
        #pragma unroll
        for (int kc = 0; kc < 4; ++kc) {
            unsigned off = (unsigned)(row * 256 + (((kc * 4 + lg) * 16) ^ ((row & 7) << 4)));
            xb[kc] = *(const bf16x8*)((const char*)xs + off);
        }
        #pragma unroll
        for (int j = 0; j < 2; ++j) {
            f32x4 a = {0.f, 0.f, 0.f, 0.f};
            #pragma unroll
            for (int kc = 0; kc < 4; ++kc) a = MFMA16(wq[j][kc], xb[kc], a);
            u32x2 pk;
            pk.x = (unsigned)f2bf(__expf(a[0])) | ((unsigned)f2bf(__expf(a[1])) << 16);
            pk.y = (unsigned)f2bf(__expf(a[2])) | ((unsigned)f2bf(__expf(a[3])) << 16);
            int ot = wid * 2 + j;
            unsigned byte = (unsigned)(row * 256 +
                (((ot * 2 + (lg >> 1)) * 16) ^ ((row & 7) << 4)) + (lg & 1) * 8);
            *(u32x2*)((char*)eqls + byte) = pk;
        }
    }
    __syncthreads();  // eqls visible; xs dead -> att may overwrite

    // ---- Phase C: out-MFMA (A=eqls, B=mpp) -> att[c][n] (128B rows, (c&7) swizzle)
    #pragma unroll
    for (int nt = 0; nt < 4; ++nt) {
        int row = nt * 16 + l15;
        bf16x8 af[4];
        #pragma unroll
        for (int kc = 0; kc < 4; ++kc) {
            unsigned off = (unsigned)(row * 256 + (((kc * 4 + lg) * 16) ^ ((row & 7) << 4)));
            af[kc] = *(const bf16x8*)((const char*)eqls + off);
        }
        #pragma unroll
        for (int ctk = 0; ctk < 2; ++ctk) {
            f32x4 a = {0.f, 0.f, 0.f, 0.f};
            #pragma unroll
            for (int kc = 0; kc < 4; ++kc) a = MFMA16(af[kc], bm[ctk][kc], a);
            int c = (wid * 2 + ctk) * 16 + l15;  // D: col=c, row=n (same as R8 k_final)
            u32x2 pk;
            pk.x = (unsigned)f2bf(a[0]) | ((unsigned)f2bf(a[1]) << 16);
            pk.y = (unsigned)f2bf(a[2]) | ((unsigned)f2bf(a[3]) << 16);
            unsigned byte = (unsigned)(c * 128 +
                (((nt * 2 + (lg >> 1)) * 16) ^ ((c & 7) << 4)) + (lg & 1) * 8);
            *(u32x2*)((char*)att + byte) = pk;
        }
    }
    __syncthreads();

    // ---- Phase D: readback + residual + coalesced store (4 c-rows per instr)
    int crow = lane >> 4;          // 0..3
    int n4 = (lane & 15) * 4;      // 4 n per lane, 64 n per 16 lanes
    #pragma unroll
    for (int it = 0; it < 8; ++it) {
        int c = wid * 32 + it * 4 + crow;
        unsigned byte = (unsigned)(c * 128 + ((n4 * 2) ^ ((c & 7) << 4)));
        u32x2 pk = *(const u32x2*)((const char*)att + byte);
        size_t off = (size_t)(b * C_ + c) * N_ + n0 + n4;
        f32x4 xv = __builtin_nontemporal_load((const f32x4*)(x + off));
        float pbv = projb[c];
        f32x4 o4;
        o4[0] = bf2f(pk.x & 0xffffu) + pbv + xv[0];
        o4[1] = bf2f(pk.x >> 16)     + pbv + xv[1];
        o4[2] = bf2f(pk.y & 0xffffu) + pbv + xv[2];
        o4[3] = bf2f(pk.y >> 16)     + pbv + xv[3];
        *(f32x4*)(out + off) = o4;
    }
}

extern "C" void kernel_launch(void* const* d_in, const int* in_sizes, int n_in,
                              void* d_out, int out_size, void* d_ws, size_t ws_size,
                              hipStream_t stream) {
    const float* x     = (const float*)d_in[0];
    const float* gnw   = (const float*)d_in[1];
    const float* gnb   = (const float*)d_in[2];
    const float* qkvw  = (const float*)d_in[3];
    const float* projw = (const float*)d_in[4];
    const float* projb = (const float*)d_in[5];
    float* out = (float*)d_out;

    char* ws = (char*)d_ws;
    ushort* wbf   = (ushort*)(ws);                // 98,304 B
    float*  qsumP = (float*)(ws + 102400);        // 524,288 B
    ushort* mpp   = (ushort*)(ws + 626688);       // 524,288 B
    float*  sc    = (float*)(ws + 1150976);       // 8,192 B (dedicated: read by k_final)
    float*  bi    = (float*)(ws + 1159168);       // 8,192 B
    float*  ctxP  = (float*)(ws + 1167360);       // 16,777,216 B (end: 17,944,576)

    k_stats<<<560,  1024, 0, stream>>>(x, gnw, gnb, sc, bi, qkvw, wbf);
    k_main <<<1024, 256,  0, stream>>>(x, wbf, sc, bi, qsumP, ctxP);
    k_red  <<<128,  256,  0, stream>>>(ctxP);
    k_comb <<<16,   256,  0, stream>>>(ctxP, qsumP, projw, mpp);
    k_final<<<4096, 256,  0, stream>>>(wbf, mpp, sc, bi, projb, x, out);
}

// Round 12
// 211.538 us; speedup vs baseline: 2.7533x; 1.0185x over previous
//
#include <hip/hip_runtime.h>

// R12: latency hiding. (1) k_main: software-prefetch next chunk's x into
// registers before the barrier (MFMA phase covers the latency). (2) k_final:
// x kept in registers from Phase A; Phase D remapped to Phase A's thread
// mapping (c=pcb*8+i, n=pk_*4+j) so the residual needs no re-read; stores
// remain 4x256B coalesced. Numerics bitwise-identical to R11.

#define B_ 16
#define C_ 128
#define N_ 16384

typedef short bf16x8 __attribute__((ext_vector_type(8)));
typedef float f32x4 __attribute__((ext_vector_type(4)));
typedef unsigned u32x2 __attribute__((ext_vector_type(2)));

__device__ __forceinline__ ushort f2bf(float f) {
    union { float f; unsigned u; } v; v.f = f;
    unsigned r = (v.u + 0x7FFFu + ((v.u >> 16) & 1u)) >> 16;
    return (ushort)r;
}
__device__ __forceinline__ float bf2f(unsigned h) {
    union { unsigned u; float f; } v; v.u = h << 16;
    return v.f;
}

// ---------------- K1: GroupNorm stats -> sc/bi ; blocks >=512 pack qkv_w ----
__global__ void k_stats(const float* __restrict__ x, const float* __restrict__ gnw,
                        const float* __restrict__ gnb, float* __restrict__ sc,
                        float* __restrict__ bi,
                        const float* __restrict__ qkvw, ushort* __restrict__ wbf) {
    int bg = blockIdx.x;
    if (bg >= 512) {  // pack 49152 weights, 48 blocks x 1024
        int i = (bg - 512) * 1024 + threadIdx.x;
        if (i < 384 * 128) wbf[i] = f2bf(qkvw[i]);
        return;
    }
    const float4* p = (const float4*)(x + (size_t)bg * (4 * N_));
    float s = 0.f, s2 = 0.f;
    for (int i = threadIdx.x; i < N_; i += 1024) {
        float4 v = p[i];
        s  += v.x + v.y + v.z + v.w;
        s2 += v.x * v.x + v.y * v.y + v.z * v.z + v.w * v.w;
    }
    #pragma unroll
    for (int d = 32; d > 0; d >>= 1) { s += __shfl_xor(s, d); s2 += __shfl_xor(s2, d); }
    __shared__ float ls[16], ls2[16];
    int wid = threadIdx.x >> 6, lane = threadIdx.x & 63;
    if (lane == 0) { ls[wid] = s; ls2[wid] = s2; }
    __syncthreads();
    if (threadIdx.x == 0) {
        float S = 0.f, S2 = 0.f;
        #pragma unroll
        for (int i = 0; i < 16; ++i) { S += ls[i]; S2 += ls2[i]; }
        float m = S / 65536.f;
        float var = S2 / 65536.f - m * m;
        float rs = rsqrtf(var + 1e-5f);
        int b = bg >> 5, g = bg & 31;
        #pragma unroll
        for (int i = 0; i < 4; ++i) {
            int c = g * 4 + i;
            float scv = rs * gnw[c];
            sc[b * 128 + c] = scv;
            bi[b * 128 + c] = gnb[c] - m * scv;
        }
    }
}

// ---------------- K2: normalize+transpose+qkv+qsum+ksm+v+MFMA-ctx (no eqT) --------
// wave0: q0..q5 | wave1: q6,q7,k(h0),k(h1) | wave2: k(h2),k(h3),v16,v17 | wave3: v18..23

#define MFMA16(A, Bv, Cc) __builtin_amdgcn_mfma_f32_16x16x32_bf16(A, Bv, Cc, 0, 0, 0)

#define DO_Q(J) do { \
    f32x4 acc = {0.f, 0.f, 0.f, 0.f}; \
    acc = MFMA16(wf[J][0], xb[0], acc); acc = MFMA16(wf[J][1], xb[1], acc); \
    acc = MFMA16(wf[J][2], xb[2], acc); acc = MFMA16(wf[J][3], xb[3], acc); \
    qacc[J][0] += __expf(acc[0]); qacc[J][1] += __expf(acc[1]); \
    qacc[J][2] += __expf(acc[2]); qacc[J][3] += __expf(acc[3]); \
} while (0)

#define DO_K(JLO, H) do { \
    f32x4 aL = {0.f, 0.f, 0.f, 0.f}, aH = {0.f, 0.f, 0.f, 0.f}; \
    aL = MFMA16(wf[JLO][0], xb[0], aL);     aH = MFMA16(wf[(JLO)+1][0], xb[0], aH); \
    aL = MFMA16(wf[JLO][1], xb[1], aL);     aH = MFMA16(wf[(JLO)+1][1], xb[1], aH); \
    aL = MFMA16(wf[JLO][2], xb[2], aL);     aH = MFMA16(wf[(JLO)+1][2], xb[2], aH); \
    aL = MFMA16(wf[JLO][3], xb[3], aL);     aH = MFMA16(wf[(JLO)+1][3], xb[3], aH); \
    float eL0 = __expf(aL[0]), eL1 = __expf(aL[1]), eL2 = __expf(aL[2]), eL3 = __expf(aL[3]); \
    float eH0 = __expf(aH[0]), eH1 = __expf(aH[1]), eH2 = __expf(aH[2]), eH3 = __expf(aH[3]); \
    float s = eL0 + eL1 + eL2 + eL3 + eH0 + eH1 + eH2 + eH3; \
    s += __shfl_xor(s, 16); s += __shfl_xor(s, 32); \
    float rinv = 1.f / s; \
    ksm[H][lg * 4 + 0][nloc] = f2bf(eL0 * rinv); \
    ksm[H][lg * 4 + 1][nloc] = f2bf(eL1 * rinv); \
    ksm[H][lg * 4 + 2][nloc] = f2bf(eL2 * rinv); \
    ksm[H][lg * 4 + 3][nloc] = f2bf(eL3 * rinv); \
    ksm[H][16 + lg * 4 + 0][nloc] = f2bf(eH0 * rinv); \
    ksm[H][16 + lg * 4 + 1][nloc] = f2bf(eH1 * rinv); \
    ksm[H][16 + lg * 4 + 2][nloc] = f2bf(eH2 * rinv); \
    ksm[H][16 + lg * 4 + 3][nloc] = f2bf(eH3 * rinv); \
} while (0)

#define DO_V(J, HV, EB) do { \
    f32x4 acc = {0.f, 0.f, 0.f, 0.f}; \
    acc = MFMA16(wf[J][0], xb[0], acc); acc = MFMA16(wf[J][1], xb[1], acc); \
    acc = MFMA16(wf[J][2], xb[2], acc); acc = MFMA16(wf[J][3], xb[3], acc); \
    vls[HV][(EB) + lg * 4 + 0][nloc] = f2bf(acc[0]); \
    vls[HV][(EB) + lg * 4 + 1][nloc] = f2bf(acc[1]); \
    vls[HV][(EB) + lg * 4 + 2][nloc] = f2bf(acc[2]); \
    vls[HV][(EB) + lg * 4 + 3][nloc] = f2bf(acc[3]); \
} while (0)

__global__ __launch_bounds__(256, 2) void k_main(
    const float* __restrict__ x, const ushort* __restrict__ wbf,
    const float* __restrict__ scA, const float* __restrict__ biA,
    float* __restrict__ qsumP, float* __restrict__ ctxP) {
    int blk = blockIdx.x;
    int b = blk >> 6, nb = blk & 63;
    int tid = threadIdx.x, wid = tid >> 6, lane = tid & 63;
    int l15 = lane & 15, lg = lane >> 4;

    __shared__ __align__(16) ushort xs[4096];        // 8 KB, [32 n][128 c] swizzled
    __shared__ __align__(16) ushort ksm[4][32][40];  // 10,240 B
    __shared__ __align__(16) ushort vls[4][32][40];  // 10,240 B

    bf16x8 wf[6][4];
    {
        const ushort* wr = wbf + (size_t)(wid * 96 + l15) * 128 + lg * 8;
        #pragma unroll
        for (int j = 0; j < 6; ++j)
            #pragma unroll
            for (int kc = 0; kc < 4; ++kc)
                wf[j][kc] = *(const bf16x8*)(wr + j * 2048 + kc * 32);
    }

    float qacc[6][4];
    #pragma unroll
    for (int j = 0; j < 6; ++j)
        #pragma unroll
        for (int r = 0; r < 4; ++r) qacc[j][r] = 0.f;
    f32x4 cacc[2][2];
    #pragma unroll
    for (int di = 0; di < 2; ++di)
        #pragma unroll
        for (int ei = 0; ei < 2; ++ei) cacc[di][ei] = (f32x4){0.f, 0.f, 0.f, 0.f};

    const int pk_ = tid & 7, pcb = tid >> 3;
    const float* xrow = x + (size_t)b * (C_ * N_) + nb * 256 + pk_ * 4;
    float scv[4], biv[4];
    #pragma unroll
    for (int i = 0; i < 4; ++i) {
        scv[i] = scA[b * 128 + pcb * 4 + i];
        biv[i] = biA[b * 128 + pcb * 4 + i];
    }
    unsigned boffj[4];
    #pragma unroll
    for (int j = 0; j < 4; ++j) {
        int n = pk_ * 4 + j;
        boffj[j] = (unsigned)(n * 256 + (((pcb >> 1) * 16) ^ ((n & 7) << 4)) + (pcb & 1) * 8);
    }

    // prefetch chunk 0
    float4 vbuf[4];
    #pragma unroll
    for (int i = 0; i < 4; ++i)
        vbuf[i] = *(const float4*)(xrow + (size_t)(pcb * 4 + i) * N_);

    for (int ch = 0; ch < 8; ++ch) {
        __syncthreads();
        // ---- Phase A: convert prefetched chunk, issue next chunk's loads
        unsigned e[4][4];
        #pragma unroll
        for (int i = 0; i < 4; ++i) {
            float s = scv[i], t = biv[i];
            e[i][0] = f2bf(vbuf[i].x * s + t);
            e[i][1] = f2bf(vbuf[i].y * s + t);
            e[i][2] = f2bf(vbuf[i].z * s + t);
            e[i][3] = f2bf(vbuf[i].w * s + t);
        }
        if (ch < 7) {
            #pragma unroll
            for (int i = 0; i < 4; ++i)
                vbuf[i] = *(const float4*)(xrow + (size_t)(pcb * 4 + i) * N_ + (ch + 1) * 32);
        }
        #pragma unroll
        for (int j = 0; j < 4; ++j) {
            u32x2 wj;
            wj.x = e[0][j] | (e[1][j] << 16);
            wj.y = e[2][j] | (e[3][j] << 16);
            *(u32x2*)((char*)xs + boffj[j]) = wj;
        }
        __syncthreads();

        // ---- Phase B: per 16-n tile (nt 0,1): xb via swizzled b128 reads
        #pragma unroll
        for (int nt = 0; nt < 2; ++nt) {
            int row = nt * 16 + l15;
            bf16x8 xb[4];
            #pragma unroll
            for (int kc = 0; kc < 4; ++kc) {
                unsigned off = (unsigned)(row * 256 +
                    (((kc * 4 + lg) * 16) ^ ((row & 7) << 4)));
                xb[kc] = *(const bf16x8*)((const char*)xs + off);
            }
            int nloc = nt * 16 + l15;

            if (wid == 0) {
                DO_Q(0); DO_Q(1); DO_Q(2); DO_Q(3); DO_Q(4); DO_Q(5);
            } else if (wid == 1) {
                DO_Q(0); DO_Q(1); DO_K(2, 0); DO_K(4, 1);
            } else if (wid == 2) {
                DO_K(0, 2); DO_K(2, 3); DO_V(4, 0, 0); DO_V(5, 0, 16);
            } else {
                DO_V(0, 1, 0); DO_V(1, 1, 16); DO_V(2, 2, 0);
                DO_V(3, 2, 16); DO_V(4, 3, 0); DO_V(5, 3, 16);
            }
        }
        __syncthreads();

        // ---- Phase C: ctx += ksm . vls^T (K=32)
        {
            bf16x8 A0 = *(const bf16x8*)&ksm[wid][l15][lg * 8];
            bf16x8 A1 = *(const bf16x8*)&ksm[wid][16 + l15][lg * 8];
            bf16x8 B0 = *(const bf16x8*)&vls[wid][l15][lg * 8];
            bf16x8 B1 = *(const bf16x8*)&vls[wid][16 + l15][lg * 8];
            cacc[0][0] = MFMA16(A0, B0, cacc[0][0]);
            cacc[0][1] = MFMA16(A0, B1, cacc[0][1]);
            cacc[1][0] = MFMA16(A1, B0, cacc[1][0]);
            cacc[1][1] = MFMA16(A1, B1, cacc[1][1]);
        }
    }

    int nq = (wid == 0) ? 6 : (wid == 1 ? 2 : 0);
    #pragma unroll
    for (int j = 0; j < 6; ++j) {
        if (j < nq) {
            #pragma unroll
            for (int r = 0; r < 4; ++r) {
                float s = qacc[j][r];
                s += __shfl_xor(s, 1); s += __shfl_xor(s, 2);
                s += __shfl_xor(s, 4); s += __shfl_xor(s, 8);
                if (l15 == 0)
                    qsumP[(size_t)blk * 128 + (wid * 6 + j) * 16 + lg * 4 + r] = s;
            }
        }
    }
    float* cp = ctxP + (size_t)blk * 4096 + wid * 1024;
    #pragma unroll
    for (int di = 0; di < 2; ++di)
        #pragma unroll
        for (int ei = 0; ei < 2; ++ei)
            #pragma unroll
            for (int r = 0; r < 4; ++r)
                cp[(di * 16 + lg * 4 + r) * 32 + ei * 16 + l15] = cacc[di][ei][r];
}

// ---------------- K2.5: reduce ctxP over the 64 n-blocks (into q=0 slice) ----
__global__ void k_red(float* __restrict__ ctxP) {
    int blk = blockIdx.x;  // B*8
    int b = blk >> 3, sl = blk & 7;
    float* base = ctxP + (size_t)b * 64 * 4096;
    #pragma unroll
    for (int r = 0; r < 2; ++r) {
        int i = sl * 512 + r * 256 + threadIdx.x;
        float s = 0.f;
        for (int q = 0; q < 64; ++q) s += base[(size_t)q * 4096 + i];
        base[i] = s;
    }
}

// ---------------- K3: combine partials, build M''[b][c][hd] bf16 ----------------
__global__ void k_comb(const float* __restrict__ ctxP, const float* __restrict__ qsumP,
                       const float* __restrict__ projw, ushort* __restrict__ mpp) {
    int b = blockIdx.x, tid = threadIdx.x;
    __shared__ float ctx[4096];
    __shared__ float qinv[128];
    for (int i = tid; i < 4096; i += 256)
        ctx[i] = ctxP[(size_t)b * 64 * 4096 + i];
    if (tid < 128) {
        float s = 0.f;
        const float* p = qsumP + (size_t)b * 64 * 128 + tid;
        for (int q = 0; q < 64; ++q) s += p[q * 128];
        qinv[tid] = 1.f / s;
    }
    __syncthreads();
    int c = tid >> 1, hd0 = (tid & 1) * 64;
    unsigned ow[32];
    for (int k = 0; k < 64; ++k) {
        int hd = hd0 + k, h = hd >> 5, d = hd & 31;
        const float* pw = projw + c * 128 + h * 32;
        const float* cx = ctx + h * 1024 + d * 32;
        float s = 0.f;
        #pragma unroll 8
        for (int e = 0; e < 32; ++e) s += pw[e] * cx[e];
        s *= qinv[hd];
        ushort bv = f2bf(s);
        if (k & 1) ow[k >> 1] |= ((unsigned)bv) << 16; else ow[k >> 1] = bv;
    }
    ushort* dst = mpp + ((size_t)(b * 128 + c)) * 128 + hd0;
    #pragma unroll
    for (int q = 0; q < 8; ++q) {
        uint4 t; t.x = ow[q * 4]; t.y = ow[q * 4 + 1]; t.z = ow[q * 4 + 2]; t.w = ow[q * 4 + 3];
        ((uint4*)dst)[q] = t;
    }
}

// ---------------- K4: recompute eq, out = eq . M''^T + proj_b + x ----------------
// 64n x 128c per block, grid 4096. x loaded ONCE (Phase A), kept in xv[8]
// registers for the Phase-D residual (Phase D uses Phase A's thread mapping).
__global__ __launch_bounds__(256) void k_final(
    const ushort* __restrict__ wbf, const ushort* __restrict__ mpp,
    const float* __restrict__ scA, const float* __restrict__ biA,
    const float* __restrict__ projb, const float* __restrict__ x,
    float* __restrict__ out) {
    int blk = blockIdx.x;
    int b = blk >> 8, nb = blk & 255;
    int tid = threadIdx.x, wid = tid >> 6, lane = tid & 63;
    int l15 = lane & 15, lg = lane >> 4;
    int n0 = nb * 64;

    __shared__ __align__(16) char lds[32768];
    ushort* xs   = (ushort*)lds;            // 16 KB, dead after Phase B
    ushort* att  = (ushort*)lds;            // 16 KB, aliases xs (barrier-separated)
    ushort* eqls = (ushort*)(lds + 16384);  // 16 KB

    // q-weight fragments (o rows 0..127): wave owns ot = wid*2, wid*2+1
    bf16x8 wq[2][4];
    #pragma unroll
    for (int j = 0; j < 2; ++j) {
        const ushort* wr = wbf + (size_t)((wid * 2 + j) * 16 + l15) * 128 + lg * 8;
        #pragma unroll
        for (int kc = 0; kc < 4; ++kc) wq[j][kc] = *(const bf16x8*)(wr + kc * 32);
    }
    // mpp fragments: wave owns ct = wid*2, wid*2+1
    bf16x8 bm[2][4];
    #pragma unroll
    for (int ctk = 0; ctk < 2; ++ctk) {
        const ushort* br = mpp + ((size_t)(b * 128 + (wid * 2 + ctk) * 16 + l15)) * 128 + lg * 8;
        #pragma unroll
        for (int kc = 0; kc < 4; ++kc) bm[ctk][kc] = *(const bf16x8*)(br + kc * 32);
    }

    // ---- Phase A: x -> xs (swizzled); raw x retained in xv[8]
    const int pk_ = tid & 15, pcb = tid >> 4;
    float4 xv[8];
    {
        const float* xrow = x + (size_t)b * (C_ * N_) + n0 + pk_ * 4;
        unsigned e[8][4];
        #pragma unroll
        for (int i = 0; i < 8; ++i) {
            int c = pcb * 8 + i;
            float s = scA[b * 128 + c], t = biA[b * 128 + c];
            xv[i] = *(const float4*)(xrow + (size_t)c * N_);
            e[i][0] = f2bf(xv[i].x * s + t);
            e[i][1] = f2bf(xv[i].y * s + t);
            e[i][2] = f2bf(xv[i].z * s + t);
            e[i][3] = f2bf(xv[i].w * s + t);
        }
        #pragma unroll
        for (int j = 0; j < 4; ++j) {
            int n = pk_ * 4 + j;
            uint4 wj;
            wj.x = e[0][j] | (e[1][j] << 16);
            wj.y = e[2][j] | (e[3][j] << 16);
            wj.z = e[4][j] | (e[5][j] << 16);
            wj.w = e[6][j] | (e[7][j] << 16);
            unsigned byte = (unsigned)(n * 256 + ((pcb * 16) ^ ((n & 7) << 4)));
            *(uint4*)((char*)xs + byte) = wj;
        }
    }
    __syncthreads();

    // ---- Phase B: q-MFMA + exp -> eqls[n][hd] (swizzled)
    #pragma unroll
    for (int nt = 0; nt < 4; ++nt) {
        int row = nt * 16 + l15;
        bf16x8 xb[4];
        #pragma unroll
        for (int kc = 0; kc < 4; ++kc) {
            unsigned off = (unsigned)(row * 256 + (((kc * 4 + lg) * 16) ^ ((row & 7) << 4)));
            xb[kc] = *(const bf16x8*)((const char*)xs + off);
        }
        #pragma unroll
        for (int j = 0; j < 2; ++j) {
            f32x4 a = {0.f, 0.f, 0.f, 0.f};
            #pragma unroll
            for (int kc = 0; kc < 4; ++kc) a = MFMA16(wq[j][kc], xb[kc], a);
            u32x2 pk;
            pk.x = (unsigned)f2bf(__expf(a[0])) | ((unsigned)f2bf(__expf(a[1])) << 16);
            pk.y = (unsigned)f2bf(__expf(a[2])) | ((unsigned)f2bf(__expf(a[3])) << 16);
            int ot = wid * 2 + j;
            unsigned byte = (unsigned)(row * 256 +
                (((ot * 2 + (lg >> 1)) * 16) ^ ((row & 7) << 4)) + (lg & 1) * 8);
            *(u32x2*)((char*)eqls + byte) = pk;
        }
    }
    __syncthreads();  // eqls visible; xs dead -> att may overwrite

    // ---- Phase C: out-MFMA (A=eqls, B=mpp) -> att[c][n] (128B rows, (c&7) swizzle)
    #pragma unroll
    for (int nt = 0; nt < 4; ++nt) {
        int row = nt * 16 + l15;
        bf16x8 af[4];
        #pragma unroll
        for (int kc = 0; kc < 4; ++kc) {
            unsigned off = (unsigned)(row * 256 + (((kc * 4 + lg) * 16) ^ ((row & 7) << 4)));
            af[kc] = *(const bf16x8*)((const char*)eqls + off);
        }
        #pragma unroll
        for (int ctk = 0; ctk < 2; ++ctk) {
            f32x4 a = {0.f, 0.f, 0.f, 0.f};
            #pragma unroll
            for (int kc = 0; kc < 4; ++kc) a = MFMA16(af[kc], bm[ctk][kc], a);
            int c = (wid * 2 + ctk) * 16 + l15;  // D: col=c, row=n
            u32x2 pk;
            pk.x = (unsigned)f2bf(a[0]) | ((unsigned)f2bf(a[1]) << 16);
            pk.y = (unsigned)f2bf(a[2]) | ((unsigned)f2bf(a[3]) << 16);
            unsigned byte = (unsigned)(c * 128 +
                (((nt * 2 + (lg >> 1)) * 16) ^ ((c & 7) << 4)) + (lg & 1) * 8);
            *(u32x2*)((char*)att + byte) = pk;
        }
    }
    __syncthreads();

    // ---- Phase D: readback + register residual + coalesced store
    // Phase A mapping: c = pcb*8+i, n = n0 + pk_*4 + j; per instr: 4 c-rows x 256B
    {
        size_t obase = (size_t)b * (C_ * N_) + n0 + pk_ * 4;
        #pragma unroll
        for (int i = 0; i < 8; ++i) {
            int c = pcb * 8 + i;
            unsigned byte = (unsigned)(c * 128 +
                (((pk_ >> 1) * 16) ^ ((c & 7) << 4)) + (pk_ & 1) * 8);
            u32x2 pk = *(const u32x2*)((const char*)att + byte);
            float pbv = projb[c];
            f32x4 o4;
            o4[0] = bf2f(pk.x & 0xffffu) + pbv + xv[i].x;
            o4[1] = bf2f(pk.x >> 16)     + pbv + xv[i].y;
            o4[2] = bf2f(pk.y & 0xffffu) + pbv + xv[i].z;
            o4[3] = bf2f(pk.y >> 16)     + pbv + xv[i].w;
            *(f32x4*)(out + obase + (size_t)c * N_) = o4;
        }
    }
}

extern "C" void kernel_launch(void* const* d_in, const int* in_sizes, int n_in,
                              void* d_out, int out_size, void* d_ws, size_t ws_size,
                              hipStream_t stream) {
    const float* x     = (const float*)d_in[0];
    const float* gnw   = (const float*)d_in[1];
    const float* gnb   = (const float*)d_in[2];
    const float* qkvw  = (const float*)d_in[3];
    const float* projw = (const float*)d_in[4];
    const float* projb = (const float*)d_in[5];
    float* out = (float*)d_out;

    char* ws = (char*)d_ws;
    ushort* wbf   = (ushort*)(ws);                // 98,304 B
    float*  qsumP = (float*)(ws + 102400);        // 524,288 B
    ushort* mpp   = (ushort*)(ws + 626688);       // 524,288 B
    float*  sc    = (float*)(ws + 1150976);       // 8,192 B
    float*  bi    = (float*)(ws + 1159168);       // 8,192 B
    float*  ctxP  = (float*)(ws + 1167360);       // 16,777,216 B (end: 17,944,576)

    k_stats<<<560,  1024, 0, stream>>>(x, gnw, gnb, sc, bi, qkvw, wbf);
    k_main <<<1024, 256,  0, stream>>>(x, wbf, sc, bi, qsumP, ctxP);
    k_red  <<<128,  256,  0, stream>>>(ctxP);
    k_comb <<<16,   256,  0, stream>>>(ctxP, qsumP, projw, mpp);
    k_final<<<4096, 256,  0, stream>>>(wbf, mpp, sc, bi, projb, x, out);
}